// Round 4
// baseline (1405.662 us; speedup 1.0000x reference)
//
#include <hip/hip_runtime.h>
#include <hip/hip_bf16.h>
#include <cmath>

// Problem constants (B,S,D,H,F fixed by the reference). Inputs f32,
// internal compute bf16 MFMA, output f32.
#define BB  2
#define SS  2048
#define DD  2048
#define HH  16
#define DKK 128      // D / H
#define FF  8192
#define FH  4096     // F / 2 (FFN split into halves)
#define MM  4096     // B * S
#define EPSL 1e-6f

typedef __attribute__((ext_vector_type(8))) short  short8;   // 8 bf16 MFMA frag
typedef __attribute__((ext_vector_type(4))) float  floatx4;  // MFMA accumulator
typedef __hip_bfloat16 bf16t;

__device__ __forceinline__ float bits2f(ushort u) {
    return __uint_as_float(((unsigned int)u) << 16);
}
__device__ __forceinline__ ushort f2bits(float f) {
    __hip_bfloat16 h = __float2bfloat16(f);
    return *reinterpret_cast<ushort*>(&h);
}

// ---------------------------------------------------------------------------
// LayerNorm (torch semantics: mean, std ddof=1, y=g*(x-m)/(std+eps)+b).
// in_f32: input external f32; else internal bf16. Params f32. Output bf16.
// ---------------------------------------------------------------------------
__global__ __launch_bounds__(256) void ln_kernel(const void* __restrict__ x,
                                                 const float* __restrict__ g,
                                                 const float* __restrict__ b,
                                                 bf16t* __restrict__ out,
                                                 int in_f32) {
    const int row = blockIdx.x;
    const int t = threadIdx.x;

    float v[8];
    if (in_f32) {
        const float* xr = (const float*)x + (size_t)row * DD;
        const float4 a4 = ((const float4*)xr)[2 * t];
        const float4 b4 = ((const float4*)xr)[2 * t + 1];
        v[0] = a4.x; v[1] = a4.y; v[2] = a4.z; v[3] = a4.w;
        v[4] = b4.x; v[5] = b4.y; v[6] = b4.z; v[7] = b4.w;
    } else {
        const ushort* xr = (const ushort*)x + (size_t)row * DD;
        union { uint4 u; ushort s[8]; } p;
        p.u = ((const uint4*)xr)[t];
#pragma unroll
        for (int i = 0; i < 8; i++) v[i] = bits2f(p.s[i]);
    }

    float sum = 0.f, sq = 0.f;
#pragma unroll
    for (int i = 0; i < 8; i++) { sum += v[i]; sq += v[i] * v[i]; }
#pragma unroll
    for (int off = 32; off > 0; off >>= 1) {
        sum += __shfl_down(sum, off);
        sq  += __shfl_down(sq, off);
    }
    __shared__ float ssum[4], ssq[4];
    const int wid = t >> 6, lane = t & 63;
    if (lane == 0) { ssum[wid] = sum; ssq[wid] = sq; }
    __syncthreads();
    if (t == 0) {
        float S = 0.f, Q = 0.f;
#pragma unroll
        for (int i = 0; i < 4; i++) { S += ssum[i]; Q += ssq[i]; }
        ssum[0] = S; ssq[0] = Q;
    }
    __syncthreads();
    const float S = ssum[0], Q = ssq[0];
    const float mean = S / (float)DD;
    float var = (Q - S * mean) / (float)(DD - 1);
    var = fmaxf(var, 0.f);
    const float inv = 1.0f / (sqrtf(var) + EPSL);

    const float4 ga = ((const float4*)g)[2 * t], gb = ((const float4*)g)[2 * t + 1];
    const float4 ba = ((const float4*)b)[2 * t], bb4 = ((const float4*)b)[2 * t + 1];
    const float gv[8] = {ga.x, ga.y, ga.z, ga.w, gb.x, gb.y, gb.z, gb.w};
    const float bv[8] = {ba.x, ba.y, ba.z, ba.w, bb4.x, bb4.y, bb4.z, bb4.w};

    union { uint4 u; ushort s[8]; } o;
#pragma unroll
    for (int i = 0; i < 8; i++) o.s[i] = f2bits((v[i] - mean) * inv * gv[i] + bv[i]);
    ((uint4*)((ushort*)out + (size_t)row * DD))[t] = o.u;
}

// ---------------------------------------------------------------------------
// Weight transpose + f32->bf16: out[c][r] = in[r0+r][c0+c], 32x32 tiles.
// grid = (nC/32, nR/32), block (32,8).
// ---------------------------------------------------------------------------
__global__ __launch_bounds__(256) void wtrans_kernel(const float* __restrict__ in,
                                                     bf16t* __restrict__ out,
                                                     int Cs, int r0, int c0, int nR) {
    __shared__ ushort tile[32][33];
    const int tx = threadIdx.x, ty = threadIdx.y;
    const int cc = blockIdx.x * 32, rr = blockIdx.y * 32;
#pragma unroll
    for (int j = 0; j < 4; j++)
        tile[ty + j * 8][tx] = f2bits(in[(size_t)(r0 + rr + ty + j * 8) * Cs + c0 + cc + tx]);
    __syncthreads();
    ushort* op = (ushort*)out;
#pragma unroll
    for (int j = 0; j < 4; j++)
        op[(size_t)(cc + ty + j * 8) * nR + rr + tx] = tile[tx][ty + j * 8];
}

// ===========================================================================
// 256x256 8-phase GEMM (guide §5 template, T2+T3+T4+T5), plain HIP.
// C[M,N] = A[M,K] @ BT[N,K]^T (+bias)(+residual)(+relu). A,BT bf16.
// 8 waves (2M x 4N), per-wave C = 128x64, BK=64, mfma_f32_16x16x32_bf16.
// LDS 128 KiB: 2 x (A[256][64] + B[256][64]) bf16, double-buffered.
//
// Swizzle: logical element (r,c) stored at LDS elem r*64 + (c ^ ((r>>2&3)<<4)).
//   - ds_read frag pattern (16 rows x b128 at col quad*8) becomes perfectly
//     bank-balanced (8 accesses/bank = b128 minimum) -- enumerated by hand.
//   - global_load_lds writes LDS linearly, so the SOURCE address is
//     pre-swizzled (rule #21 / m201 stage_rc pattern).
//
// Stage schedule (race-free by construction): tile halves = the row regions
// each quadrant phase reads (A: (r>>6)&1, B: (r>>5)&1). A half staged in
// phase p overwrites a region whose last read is phase <= p-1; the trailing
// per-phase barrier (after every wave's lgkmcnt(0)) orders read-completion
// before stage-issue, and a DMA write cannot land before issue.
// Counted vmcnt(4) at phases 4/8 keeps 2 half-tiles (4 loads) in flight
// across every tile boundary (never drains to 0 except the final iteration).
//
// out_mode: 0 = plain to C (c_f32 selects f32/bf16), with optional
//           residual/relu/bias;
//           1 = per-(b,h)-transposed V layout to C (bf16);
//           2 = fused KV: cols [0,DD) plain bf16 -> C (bias), cols [DD,2DD)
//               V-layout -> C2 (bias2). Block-uniform branch (n0 % DD == 0).
// ===========================================================================
template<int IB>   // IB=6: A (64-row interleave); IB=5: B (32-row interleave)
__device__ __forceinline__ void stage_half(const ushort* __restrict__ g, int Kx,
                                           ushort* lds, int h, int wid, int lane) {
#pragma unroll
    for (int l = 0; l < 2; l++) {
        const int c = wid * 2 + l;            // chunk 0..15, 8 rows x 128 B each
        const int rs = (IB == 6) ? (((c & 8) ? 128 : 0) + h * 64 + (c & 7) * 8)
                                 : ((c >> 2) * 64 + h * 32 + (c & 3) * 8);
        const int row = rs + (lane >> 3);
        const int colb = ((lane & 7) * 16) ^ (((row >> 2) & 3) << 5);  // pre-swizzled src
        const ushort* gp = g + (size_t)row * Kx + (colb >> 1);
        __builtin_amdgcn_global_load_lds(
            (const __attribute__((address_space(1))) void*)gp,
            (__attribute__((address_space(3))) void*)(lds + rs * 64), 16, 0, 0);
    }
}

#define VMCNT4 asm volatile("s_waitcnt vmcnt(4)" ::: "memory")
#define VMCNT0 asm volatile("s_waitcnt vmcnt(0)" ::: "memory")

#define STGA(buf, kt, h) stage_half<6>(gAu + (size_t)(kt) * 64, Kx, &LAf[(buf) * (256 * 64)], (h), wid, lane)
#define STGB(buf, kt, h) stage_half<5>(gBu + (size_t)(kt) * 64, Kx, &LBf[(buf) * (256 * 64)], (h), wid, lane)

// One phase: 12 ds_read_b128 || 1 half-tile stage -> barrier -> lgkmcnt(0)
// -> setprio(1) 16 MFMA setprio(0) -> [vmcnt] -> barrier.
#define PHASE(BUF, MH, NH, STAGE_STMT, WAIT_STMT)                                   \
    do {                                                                            \
        const ushort* LAc = &LAf[(BUF) * (256 * 64)];                               \
        const ushort* LBc = &LBf[(BUF) * (256 * 64)];                               \
        short8 af[4][2], bfr[2][2];                                                 \
        _Pragma("unroll") for (int i = 0; i < 4; i++) {                             \
            const int ar = arow0 + ((MH) * 4 + i) * 16;                             \
            af[i][0] = *(const short8*)&LAc[ar * 64 + swz0];                        \
            af[i][1] = *(const short8*)&LAc[ar * 64 + swz1];                        \
        }                                                                           \
        _Pragma("unroll") for (int j = 0; j < 2; j++) {                             \
            const int br = brow0 + ((NH) * 2 + j) * 16;                             \
            bfr[j][0] = *(const short8*)&LBc[br * 64 + swz0];                       \
            bfr[j][1] = *(const short8*)&LBc[br * 64 + swz1];                       \
        }                                                                           \
        STAGE_STMT;                                                                 \
        asm volatile("s_waitcnt lgkmcnt(8)" ::: "memory");                          \
        __builtin_amdgcn_s_barrier();                                               \
        asm volatile("s_waitcnt lgkmcnt(0)" ::: "memory");                          \
        __builtin_amdgcn_s_setprio(1);                                              \
        _Pragma("unroll") for (int i = 0; i < 4; i++)                               \
            _Pragma("unroll") for (int j = 0; j < 2; j++) {                         \
                acc[(MH) * 4 + i][(NH) * 2 + j] =                                   \
                    __builtin_amdgcn_mfma_f32_16x16x32_bf16(                        \
                        af[i][0], bfr[j][0], acc[(MH) * 4 + i][(NH) * 2 + j], 0, 0, 0); \
                acc[(MH) * 4 + i][(NH) * 2 + j] =                                   \
                    __builtin_amdgcn_mfma_f32_16x16x32_bf16(                        \
                        af[i][1], bfr[j][1], acc[(MH) * 4 + i][(NH) * 2 + j], 0, 0, 0); \
            }                                                                       \
        __builtin_amdgcn_s_setprio(0);                                              \
        WAIT_STMT;                                                                  \
        __builtin_amdgcn_s_barrier();                                               \
    } while (0)

__global__ __launch_bounds__(512, 2) void gemm256(const bf16t* __restrict__ A,
                                                  const bf16t* __restrict__ BT,
                                                  const float* __restrict__ bias,
                                                  const float* __restrict__ bias2,
                                                  const void* __restrict__ residual, int res_mode,
                                                  void* __restrict__ C, void* __restrict__ C2,
                                                  int c_f32, int Nx, int Kx,
                                                  int relu, int out_mode) {
    __shared__ __align__(16) ushort LAf[2 * 256 * 64];   // 64 KiB
    __shared__ __align__(16) ushort LBf[2 * 256 * 64];   // 64 KiB

    const int tid = threadIdx.x;
    const int wid = tid >> 6, lane = tid & 63;
    const int m16 = lane & 15, quad = lane >> 4;
    const int wr = wid >> 2, wc = wid & 3;            // 2 x 4 wave grid
    const int m0 = blockIdx.y * 256, n0 = blockIdx.x * 256;

    const ushort* gAu = (const ushort*)A + (size_t)m0 * Kx;
    const ushort* gBu = (const ushort*)BT + (size_t)n0 * Kx;

    floatx4 acc[8][4];
#pragma unroll
    for (int i = 0; i < 8; i++)
#pragma unroll
        for (int j = 0; j < 4; j++) acc[i][j] = (floatx4){0.f, 0.f, 0.f, 0.f};

    // per-thread swizzled k-column offsets (elements) for both k-steps
    const int xsw = (m16 >> 2) & 3;
    const int swz0 = (quad * 8) ^ (xsw << 4);
    const int swz1 = (32 + quad * 8) ^ (xsw << 4);
    const int arow0 = wr * 128 + m16;
    const int brow0 = wc * 64 + m16;

    const int nk = Kx / 64;

    // Prologue: tile0 all 4 halves + tile1 {B0,A0}; drain tile0, keep 4 loads.
    STGB(0, 0, 0); STGA(0, 0, 0); STGA(0, 0, 1); STGB(0, 0, 1);
    STGB(1, 1, 0); STGA(1, 1, 0);
    VMCNT4;
    __builtin_amdgcn_s_barrier();

    for (int t = 0; t < nk; t += 2) {
        const bool pf = (t + 2 < nk);
        // ---- tile t (buf0): quads (0,0),(1,0),(0,1),(1,1) ----
        PHASE(0, 0, 0, { STGA(1, t + 1, 1); }, {});
        PHASE(0, 1, 0, { STGB(1, t + 1, 1); }, {});
        PHASE(0, 0, 1, { if (pf) STGB(0, t + 2, 0); }, {});
        PHASE(0, 1, 1, { if (pf) STGA(0, t + 2, 0); },
              { if (pf) { VMCNT4; } else { VMCNT0; } });
        // ---- tile t+1 (buf1) ----
        PHASE(1, 0, 0, { if (pf) STGA(0, t + 2, 1); }, {});
        PHASE(1, 1, 0, { if (pf) STGB(0, t + 2, 1); }, {});
        PHASE(1, 0, 1, { if (pf) STGB(1, t + 3, 0); }, {});
        PHASE(1, 1, 1, { if (pf) STGA(1, t + 3, 0); },
              { if (pf) { VMCNT4; } });
    }

    // Epilogue: C/D layout col=lane&15, row=quad*4+reg (m89-verified).
#pragma unroll
    for (int i = 0; i < 8; i++) {
        const int row = m0 + wr * 128 + i * 16 + quad * 4;
#pragma unroll
        for (int j = 0; j < 4; j++) {
            const int col = n0 + wc * 64 + j * 16 + m16;
            const bool isv = (out_mode == 1) || (out_mode == 2 && col >= DD);
            const int cv = (out_mode == 2 && col >= DD) ? col - DD : col;
            const float bb = (out_mode == 2 && col >= DD)
                                 ? bias2[cv]
                                 : (bias ? bias[col] : 0.f);
#pragma unroll
            for (int r = 0; r < 4; r++) {
                float v = acc[i][j][r] + bb;
                if (isv) {
                    const int bb2 = (row + r) >> 11, s = (row + r) & 2047;
                    const int hh2 = cv >> 7, dd2 = cv & 127;
                    ushort* dst = (ushort*)((out_mode == 2) ? C2 : C);
                    dst[((size_t)(bb2 * HH + hh2) * DKK + dd2) * SS + s] = f2bits(v);
                } else {
                    const size_t idx = (size_t)(row + r) * Nx + cv;
                    if (res_mode == 1)      v += ((const float*)residual)[idx];
                    else if (res_mode == 2) v += bits2f(((const ushort*)residual)[idx]);
                    if (relu) v = fmaxf(v, 0.f);
                    if (c_f32) ((float*)C)[idx] = v;
                    else       ((ushort*)C)[idx] = f2bits(v);
                }
            }
        }
    }
}

// ---------------------------------------------------------------------------
// Flash attention: block = (64 q-rows, h, b), 4 waves; online softmax;
// P via LDS C->A relayout. LDS strides padded for conflict-free access.
// Mask all-ones -> skipped. (Unchanged this round; next target.)
// ---------------------------------------------------------------------------
#define SQK 144
#define SV  72
#define SP  72
__global__ __launch_bounds__(256) void attn_kernel(const bf16t* __restrict__ q,
                                                   const bf16t* __restrict__ k,
                                                   const bf16t* __restrict__ vT,
                                                   bf16t* __restrict__ o) {
    __shared__ __align__(16) ushort Qt[64 * SQK];
    __shared__ __align__(16) ushort Kt[64 * SQK];
    __shared__ __align__(16) ushort Vt[128 * SV];
    __shared__ __align__(16) ushort Pt[4][16 * SP];

    const int tid = threadIdx.x;
    const int wid = tid >> 6, lane = tid & 63;
    const int m16 = lane & 15, quad = lane >> 4;
    const int qt = blockIdx.x, h = blockIdx.y, b = blockIdx.z;
    const int q0 = qt * 64;

    const ushort* qu = (const ushort*)q;
    const ushort* ku = (const ushort*)k;
    const ushort* vu = (const ushort*)vT;

#pragma unroll
    for (int it = 0; it < 4; it++) {
        const int c0 = tid + it * 256;
        const int r = c0 >> 4, cc = (c0 & 15) * 8;
        *(uint4*)&Qt[r * SQK + cc] =
            *(const uint4*)(qu + (size_t)(b * SS + q0 + r) * DD + h * DKK + cc);
    }

    float m_r[4], l_r[4];
    floatx4 acc_o[8];
#pragma unroll
    for (int r = 0; r < 4; r++) { m_r[r] = -1e30f; l_r[r] = 0.f; }
#pragma unroll
    for (int t = 0; t < 8; t++) acc_o[t] = (floatx4){0.f, 0.f, 0.f, 0.f};

    const float scale = 0.08838834764831845f;   // 1/sqrt(128)

    for (int kt2 = 0; kt2 < SS / 64; kt2++) {
        __syncthreads();
#pragma unroll
        for (int it = 0; it < 4; it++) {
            const int c0 = tid + it * 256;
            const int r = c0 >> 4, cc = (c0 & 15) * 8;
            *(uint4*)&Kt[r * SQK + cc] =
                *(const uint4*)(ku + (size_t)(b * SS + kt2 * 64 + r) * DD + h * DKK + cc);
            const int r2 = c0 >> 3, cc2 = (c0 & 7) * 8;
            *(uint4*)&Vt[r2 * SV + cc2] =
                *(const uint4*)(vu + (size_t)((b * HH + h) * DKK + r2) * SS + kt2 * 64 + cc2);
        }
        __syncthreads();

        short8 af[4];
#pragma unroll
        for (int kk = 0; kk < 4; kk++)
            af[kk] = *(const short8*)&Qt[(wid * 16 + m16) * SQK + kk * 32 + quad * 8];
        floatx4 sacc[4];
#pragma unroll
        for (int j = 0; j < 4; j++) {
            sacc[j] = (floatx4){0.f, 0.f, 0.f, 0.f};
#pragma unroll
            for (int kk = 0; kk < 4; kk++) {
                short8 bfk = *(const short8*)&Kt[(j * 16 + m16) * SQK + kk * 32 + quad * 8];
                sacc[j] = __builtin_amdgcn_mfma_f32_16x16x32_bf16(af[kk], bfk, sacc[j], 0, 0, 0);
            }
        }
#pragma unroll
        for (int r = 0; r < 4; r++) {
            float s0 = sacc[0][r] * scale, s1 = sacc[1][r] * scale;
            float s2 = sacc[2][r] * scale, s3 = sacc[3][r] * scale;
            float mx = fmaxf(fmaxf(s0, s1), fmaxf(s2, s3));
#pragma unroll
            for (int off = 1; off < 16; off <<= 1) mx = fmaxf(mx, __shfl_xor(mx, off));
            const float mnew = fmaxf(m_r[r], mx);
            const float alpha = __expf(m_r[r] - mnew);
            m_r[r] = mnew;
            const float p0 = __expf(s0 - mnew), p1 = __expf(s1 - mnew);
            const float p2 = __expf(s2 - mnew), p3 = __expf(s3 - mnew);
            float rs = p0 + p1 + p2 + p3;
#pragma unroll
            for (int off = 1; off < 16; off <<= 1) rs += __shfl_xor(rs, off);
            l_r[r] = l_r[r] * alpha + rs;
#pragma unroll
            for (int t = 0; t < 8; t++) acc_o[t][r] *= alpha;
            const int prow = (quad * 4 + r) * SP;
            Pt[wid][prow + 0 * 16 + m16] = f2bits(p0);
            Pt[wid][prow + 1 * 16 + m16] = f2bits(p1);
            Pt[wid][prow + 2 * 16 + m16] = f2bits(p2);
            Pt[wid][prow + 3 * 16 + m16] = f2bits(p3);
        }
#pragma unroll
        for (int kk2 = 0; kk2 < 2; kk2++) {
            short8 ap = *(const short8*)&Pt[wid][m16 * SP + kk2 * 32 + quad * 8];
#pragma unroll
            for (int t = 0; t < 8; t++) {
                short8 bv = *(const short8*)&Vt[(t * 16 + m16) * SV + kk2 * 32 + quad * 8];
                acc_o[t] = __builtin_amdgcn_mfma_f32_16x16x32_bf16(ap, bv, acc_o[t], 0, 0, 0);
            }
        }
    }

    ushort* ou = (ushort*)o;
#pragma unroll
    for (int t = 0; t < 8; t++) {
#pragma unroll
        for (int r = 0; r < 4; r++) {
            const float v = acc_o[t][r] / l_r[r];
            ou[(size_t)(b * SS + q0 + wid * 16 + quad * 4 + r) * DD + h * DKK + t * 16 + m16] = f2bits(v);
        }
    }
}

// ---------------------------------------------------------------------------
// Orchestration. ws: 4 x 16 MiB slots (64 MiB, proven safe). Stream order
// guarantees sequential kernel execution -> safe slot reuse.
//   S0: n         -> woT (after O-wtrans) -> n2 (after LN2)
//   S1: k         -> h lower half (FFN; h spans S1+S2 = 32 MiB)
//   S2: wqT, then wkvT (16 MiB) -> a (after attn) -> h upper half
//   S3: vT        -> w1Th / w2Th per FFN half
//   d_out: q (bf16 scratch) -> x1 (f32, after O-proj) -> final f32 out
// ---------------------------------------------------------------------------
extern "C" void kernel_launch(void* const* d_in, const int* in_sizes, int n_in,
                              void* d_out, int out_size, void* d_ws, size_t ws_size,
                              hipStream_t stream) {
    const float* x   = (const float*)d_in[0];
    // d_in[1] = mask (int32, all ones) — no-op in reference, skipped
    const float* wq = (const float*)d_in[2];  const float* bq = (const float*)d_in[3];
    const float* wk = (const float*)d_in[4];  const float* bk = (const float*)d_in[5];
    const float* wv = (const float*)d_in[6];  const float* bv = (const float*)d_in[7];
    const float* wo = (const float*)d_in[8];  const float* bo = (const float*)d_in[9];
    const float* w1 = (const float*)d_in[10]; const float* b1 = (const float*)d_in[11];
    const float* w2 = (const float*)d_in[12]; const float* b2 = (const float*)d_in[13];
    const float* g1 = (const float*)d_in[14]; const float* lb1 = (const float*)d_in[15];
    const float* g2 = (const float*)d_in[16]; const float* lb2 = (const float*)d_in[17];

    char* ws = (char*)d_ws;
    bf16t* S0 = (bf16t*)(ws);
    bf16t* S1 = (bf16t*)(ws + (16u << 20));
    bf16t* S2 = (bf16t*)(ws + (32u << 20));
    bf16t* S3 = (bf16t*)(ws + (48u << 20));

    bf16t* n_buf  = S0;
    bf16t* k_buf  = S1;
    bf16t* wT_buf = S2;              // wq^T (8 MiB), then wkv^T (16 MiB)
    bf16t* vT_buf = S3;
    bf16t* q_buf  = (bf16t*)d_out;   // scratch (d_out = 33.5 MB f32)
    bf16t* a_buf  = S2;              // after attn (wkvT dead)
    bf16t* woT    = S0;              // after QKV (n dead)
    bf16t* n2_buf = S0;              // after LN2 (woT dead)
    bf16t* h_buf  = S1;              // FFN half activations, 32 MiB (S1+S2)
    bf16t* wfT    = S3;              // FFN weight transposes (vT dead)

    const dim3 tb(32, 8);
    const dim3 grT(DD / 32, DD / 32);          // 2048x2048 transposes
    const dim3 gr256(DD / 256, MM / 256);      // (8, 16) for N=2048 GEMMs
    const dim3 grKV(2 * DD / 256, MM / 256);   // (16, 16) fused KV, full CU coverage

    // LN1: x(f32) -> n(bf16)
    ln_kernel<<<MM, 256, 0, stream>>>(x, g1, lb1, n_buf, 1);

    // Q projection first (wqT occupies S2 before wkvT overwrites it)
    wtrans_kernel<<<grT, tb, 0, stream>>>(wq, wT_buf, DD, 0, 0, DD);
    gemm256<<<gr256, 512, 0, stream>>>(n_buf, wT_buf, bq, nullptr, nullptr, 0,
                                       q_buf, nullptr, 0, DD, DD, 0, 0);

    // Fused KV: wkvT = [wk^T ; wv^T] (16 MiB in S2), one N=4096 GEMM (256 wg)
    wtrans_kernel<<<grT, tb, 0, stream>>>(wk, wT_buf, DD, 0, 0, DD);
    wtrans_kernel<<<grT, tb, 0, stream>>>(wv, wT_buf + (size_t)DD * DD, DD, 0, 0, DD);
    gemm256<<<grKV, 512, 0, stream>>>(n_buf, wT_buf, bk, bv, nullptr, 0,
                                      k_buf, vT_buf, 0, DD, DD, 0, 2);

    // attention -> a (S2; wkvT dead)
    attn_kernel<<<dim3(SS / 64, HH, BB), 256, 0, stream>>>(q_buf, k_buf, vT_buf, a_buf);

    // x1 = x + a @ wo + bo -> d_out (f32); residual x external f32
    wtrans_kernel<<<grT, tb, 0, stream>>>(wo, woT, DD, 0, 0, DD);
    gemm256<<<gr256, 512, 0, stream>>>(a_buf, woT, bo, nullptr, x, 1,
                                       d_out, nullptr, 1, DD, DD, 0, 0);

    // LN2: x1(f32, in d_out) -> n2
    ln_kernel<<<MM, 256, 0, stream>>>(d_out, g2, lb2, n2_buf, 1);

    // FFN in two F-halves: d_out = x1 + relu(n2@w1+b1) @ w2 + b2 (f32 in place)
    for (int hf = 0; hf < 2; hf++) {
        const int f0 = hf * FH;
        // w1Th = w1[:, f0:f0+FH]^T (bf16 [FH][D])
        wtrans_kernel<<<dim3(FH / 32, DD / 32), tb, 0, stream>>>(w1, wfT, FF, 0, f0, DD);
        // h = relu(n2 @ w1Th + b1[f0:]) (bf16 [M][FH], 32 MiB in S1+S2)
        gemm256<<<dim3(FH / 256, MM / 256), 512, 0, stream>>>(
            n2_buf, wfT, b1 + f0, nullptr, nullptr, 0, h_buf, nullptr, 0, FH, DD, 1, 0);
        // w2Th = w2[f0:f0+FH, :]^T (bf16 [D][FH])
        wtrans_kernel<<<dim3(DD / 32, FH / 32), tb, 0, stream>>>(w2, wfT, DD, f0, 0, FH);
        // d_out += h @ w2Th (+b2 on first half); residual = d_out (x1 f32), in-place
        gemm256<<<gr256, 512, 0, stream>>>(
            h_buf, wfT, hf == 0 ? b2 : nullptr, nullptr, d_out, 1,
            d_out, nullptr, 1, DD, FH, 0, 0);
    }
}

// Round 5
// 1150.276 us; speedup vs baseline: 1.2220x; 1.2220x over previous
//
#include <hip/hip_runtime.h>
#include <hip/hip_bf16.h>
#include <cmath>

// Problem constants (B,S,D,H,F fixed by the reference). Inputs f32,
// internal compute bf16 MFMA, output f32.
#define BB  2
#define SS  2048
#define DD  2048
#define HH  16
#define DKK 128      // D / H
#define FF  8192
#define FH  4096     // F / 2 (FFN split into halves)
#define MM  4096     // B * S
#define EPSL 1e-6f

typedef __attribute__((ext_vector_type(8))) short  short8;   // 8 bf16 MFMA frag
typedef __attribute__((ext_vector_type(4))) float  floatx4;  // MFMA accumulator
typedef __hip_bfloat16 bf16t;

__device__ __forceinline__ float bits2f(ushort u) {
    return __uint_as_float(((unsigned int)u) << 16);
}
__device__ __forceinline__ ushort f2bits(float f) {
    __hip_bfloat16 h = __float2bfloat16(f);
    return *reinterpret_cast<ushort*>(&h);
}

// ---------------------------------------------------------------------------
// LayerNorm (torch semantics: mean, std ddof=1, y=g*(x-m)/(std+eps)+b).
// ---------------------------------------------------------------------------
__global__ __launch_bounds__(256) void ln_kernel(const void* __restrict__ x,
                                                 const float* __restrict__ g,
                                                 const float* __restrict__ b,
                                                 bf16t* __restrict__ out,
                                                 int in_f32) {
    const int row = blockIdx.x;
    const int t = threadIdx.x;

    float v[8];
    if (in_f32) {
        const float* xr = (const float*)x + (size_t)row * DD;
        const float4 a4 = ((const float4*)xr)[2 * t];
        const float4 b4 = ((const float4*)xr)[2 * t + 1];
        v[0] = a4.x; v[1] = a4.y; v[2] = a4.z; v[3] = a4.w;
        v[4] = b4.x; v[5] = b4.y; v[6] = b4.z; v[7] = b4.w;
    } else {
        const ushort* xr = (const ushort*)x + (size_t)row * DD;
        union { uint4 u; ushort s[8]; } p;
        p.u = ((const uint4*)xr)[t];
#pragma unroll
        for (int i = 0; i < 8; i++) v[i] = bits2f(p.s[i]);
    }

    float sum = 0.f, sq = 0.f;
#pragma unroll
    for (int i = 0; i < 8; i++) { sum += v[i]; sq += v[i] * v[i]; }
#pragma unroll
    for (int off = 32; off > 0; off >>= 1) {
        sum += __shfl_down(sum, off);
        sq  += __shfl_down(sq, off);
    }
    __shared__ float ssum[4], ssq[4];
    const int wid = t >> 6, lane = t & 63;
    if (lane == 0) { ssum[wid] = sum; ssq[wid] = sq; }
    __syncthreads();
    if (t == 0) {
        float S = 0.f, Q = 0.f;
#pragma unroll
        for (int i = 0; i < 4; i++) { S += ssum[i]; Q += ssq[i]; }
        ssum[0] = S; ssq[0] = Q;
    }
    __syncthreads();
    const float S = ssum[0], Q = ssq[0];
    const float mean = S / (float)DD;
    float var = (Q - S * mean) / (float)(DD - 1);
    var = fmaxf(var, 0.f);
    const float inv = 1.0f / (sqrtf(var) + EPSL);

    const float4 ga = ((const float4*)g)[2 * t], gb = ((const float4*)g)[2 * t + 1];
    const float4 ba = ((const float4*)b)[2 * t], bb4 = ((const float4*)b)[2 * t + 1];
    const float gv[8] = {ga.x, ga.y, ga.z, ga.w, gb.x, gb.y, gb.z, gb.w};
    const float bv[8] = {ba.x, ba.y, ba.z, ba.w, bb4.x, bb4.y, bb4.z, bb4.w};

    union { uint4 u; ushort s[8]; } o;
#pragma unroll
    for (int i = 0; i < 8; i++) o.s[i] = f2bits((v[i] - mean) * inv * gv[i] + bv[i]);
    ((uint4*)((ushort*)out + (size_t)row * DD))[t] = o.u;
}

// ---------------------------------------------------------------------------
// Weight transpose + f32->bf16: out[c][r] = in[r0+r][c0+c], 32x32 tiles.
// ---------------------------------------------------------------------------
__global__ __launch_bounds__(256) void wtrans_kernel(const float* __restrict__ in,
                                                     bf16t* __restrict__ out,
                                                     int Cs, int r0, int c0, int nR) {
    __shared__ ushort tile[32][33];
    const int tx = threadIdx.x, ty = threadIdx.y;
    const int cc = blockIdx.x * 32, rr = blockIdx.y * 32;
#pragma unroll
    for (int j = 0; j < 4; j++)
        tile[ty + j * 8][tx] = f2bits(in[(size_t)(r0 + rr + ty + j * 8) * Cs + c0 + cc + tx]);
    __syncthreads();
    ushort* op = (ushort*)out;
#pragma unroll
    for (int j = 0; j < 4; j++)
        op[(size_t)(cc + ty + j * 8) * nR + rr + tx] = tile[tx][ty + j * 8];
}

// ===========================================================================
// 256x256 8-phase GEMM, round-5 rework after r4 post-mortem:
//  - Swizzle fixed to the HW-verified shape (G4 attn case): 16B-chunk index
//    XOR (row&7). Read: chunk (quad+4ks) ^ (m16&7); DMA source chunk
//    (lane&7) ^ (lane>>3). Element-traced for consistency.
//  - Fragment registers held across phases: af[4][2] (A quadrant), bfr0/bfr1
//    (B halves) -> 24 ds_read_b128 per K-tile/wave (minimal), was 48.
//  - Phase order per K-tile: (0,0) (0,1) (1,0) (1,1); reads [12,4,8,0].
//  - Uniform stage schedule, 1 half-stage/phase; steady-state vmcnt(10) at
//    phases 1,2,4,5,6,8 (10-12 loads in flight); epilogue drains 10/8/4/2/0.
//  - sched_barrier(0) after every s_barrier: no LDS op crosses a barrier
//    (cross-wave publication safety, rule #18 analog).
//  - Bijective XCD swizzle on linearized block id (all grids % 8 == 0).
// ===========================================================================
template<int IB>   // IB=6: A (64-row interleave); IB=5: B (32-row interleave)
__device__ __forceinline__ void stage_half(const ushort* __restrict__ g, int Kx,
                                           ushort* lds, int h, int wid, int lane) {
#pragma unroll
    for (int l = 0; l < 2; l++) {
        const int c = wid * 2 + l;            // chunk 0..15, 8 rows x 128 B each
        const int rs = (IB == 6) ? (((c & 8) ? 128 : 0) + h * 64 + (c & 7) * 8)
                                 : ((c >> 2) * 64 + h * 32 + (c & 3) * 8);
        const int row = rs + (lane >> 3);
        const int csrc = (lane & 7) ^ (lane >> 3);   // pre-swizzled source chunk
        const ushort* gp = g + (size_t)row * Kx + csrc * 8;
        __builtin_amdgcn_global_load_lds(
            (const __attribute__((address_space(1))) void*)gp,
            (__attribute__((address_space(3))) void*)(lds + rs * 64), 16, 0, 0);
    }
}

#define VMW10 asm volatile("s_waitcnt vmcnt(10)" ::: "memory")
#define VMW8  asm volatile("s_waitcnt vmcnt(8)" ::: "memory")
#define VMW4  asm volatile("s_waitcnt vmcnt(4)" ::: "memory")
#define VMW2  asm volatile("s_waitcnt vmcnt(2)" ::: "memory")
#define VMW0  asm volatile("s_waitcnt vmcnt(0)" ::: "memory")
#define LGK0  asm volatile("s_waitcnt lgkmcnt(0)" ::: "memory")
#define BARS  do { __builtin_amdgcn_s_barrier(); __builtin_amdgcn_sched_barrier(0); } while (0)

#define STGA(buf, kt, h) stage_half<6>(gAu + (size_t)(kt) * 64, Kx, &LAf[(buf) * (256 * 64)], (h), wid, lane)
#define STGB(buf, kt, h) stage_half<5>(gBu + (size_t)(kt) * 64, Kx, &LBf[(buf) * (256 * 64)], (h), wid, lane)

#define LDAF(BUF, MH)                                                     \
    do { const ushort* Lp = &LAf[(BUF) * (256 * 64)];                     \
        _Pragma("unroll") for (int i = 0; i < 4; i++) {                   \
            const int rr = (arow0 + ((MH) * 4 + i) * 16) * 64;            \
            af[i][0] = *(const short8*)&Lp[rr + swz0];                    \
            af[i][1] = *(const short8*)&Lp[rr + swz1];                    \
        } } while (0)

#define LDB(BUF, NH, DST)                                                 \
    do { const ushort* Lp = &LBf[(BUF) * (256 * 64)];                     \
        _Pragma("unroll") for (int j = 0; j < 2; j++) {                   \
            const int rr = (brow0 + ((NH) * 2 + j) * 16) * 64;            \
            DST[j][0] = *(const short8*)&Lp[rr + swz0];                   \
            DST[j][1] = *(const short8*)&Lp[rr + swz1];                   \
        } } while (0)

#define MFMAQ(MH, NH, BSRC)                                               \
    do { __builtin_amdgcn_s_setprio(1);                                   \
        _Pragma("unroll") for (int i = 0; i < 4; i++)                     \
        _Pragma("unroll") for (int j = 0; j < 2; j++) {                   \
            acc[(MH) * 4 + i][(NH) * 2 + j] =                             \
                __builtin_amdgcn_mfma_f32_16x16x32_bf16(                  \
                    af[i][0], BSRC[j][0], acc[(MH) * 4 + i][(NH) * 2 + j], 0, 0, 0); \
            acc[(MH) * 4 + i][(NH) * 2 + j] =                             \
                __builtin_amdgcn_mfma_f32_16x16x32_bf16(                  \
                    af[i][1], BSRC[j][1], acc[(MH) * 4 + i][(NH) * 2 + j], 0, 0, 0); \
        }                                                                 \
        __builtin_amdgcn_s_setprio(0); } while (0)

__global__ __launch_bounds__(512, 2) void gemm256(const bf16t* __restrict__ A,
                                                  const bf16t* __restrict__ BT,
                                                  const float* __restrict__ bias,
                                                  const float* __restrict__ bias2,
                                                  const void* __restrict__ residual, int res_mode,
                                                  void* __restrict__ C, void* __restrict__ C2,
                                                  int c_f32, int Nx, int Kx,
                                                  int relu, int out_mode) {
    __shared__ __align__(16) ushort LAf[2 * 256 * 64];   // 64 KiB
    __shared__ __align__(16) ushort LBf[2 * 256 * 64];   // 64 KiB

    const int tid = threadIdx.x;
    const int wid = tid >> 6, lane = tid & 63;
    const int m16 = lane & 15, quad = lane >> 4;
    const int wr = wid >> 2, wc = wid & 3;            // 2 x 4 wave grid

    // Bijective XCD-aware block swizzle (nwg % 8 == 0 for all our grids)
    const int gx = gridDim.x;
    const int nwg = gx * gridDim.y;
    const int orig = blockIdx.y * gx + blockIdx.x;
    const int bid = (orig & 7) * (nwg >> 3) + (orig >> 3);
    const int m0 = (bid / gx) * 256, n0 = (bid % gx) * 256;

    const ushort* gAu = (const ushort*)A + (size_t)m0 * Kx;
    const ushort* gBu = (const ushort*)BT + (size_t)n0 * Kx;

    floatx4 acc[8][4];
#pragma unroll
    for (int i = 0; i < 8; i++)
#pragma unroll
        for (int j = 0; j < 4; j++) acc[i][j] = (floatx4){0.f, 0.f, 0.f, 0.f};

    // Swizzled per-lane k-chunk offsets (elems): chunk (quad+4ks) ^ (row&7),
    // row&7 == m16&7 for every fragment row this lane touches.
    const int sw = m16 & 7;
    const int swz0 = (quad ^ sw) << 3;
    const int swz1 = ((quad + 4) ^ sw) << 3;
    const int arow0 = wr * 128 + m16;
    const int brow0 = wc * 64 + m16;

    const int nk = Kx / 64;

    // Prologue: o1..o7 = A0h0,B0h0,B0h1,A0h1,A1h0,B1h0,B1h1 (A1h1 staged ph1)
    STGA(0, 0, 0); STGB(0, 0, 0); STGB(0, 0, 1); STGA(0, 0, 1);
    STGA(1, 1, 0); STGB(1, 1, 0); STGB(1, 1, 1);
    VMW10;
    BARS;

    short8 af[4][2], bfr0[2][2], bfr1[2][2];

    for (int t = 0; t < nk; t += 2) {
        const bool pf = (t + 2 < nk);
        // ---- tile t (buf0) ----
        // ph1 (0,0)
        LDAF(0, 0); LDB(0, 0, bfr0);
        STGA(1, t + 1, 1);                       // A(b)h1, read ph7
        BARS; LGK0; MFMAQ(0, 0, bfr0);
        VMW10; BARS;
        // ph2 (0,1)
        LDB(0, 1, bfr1);
        if (pf) STGA(0, t + 2, 0);
        BARS; LGK0; MFMAQ(0, 1, bfr1);
        if (pf) { VMW10; } else { VMW8; }
        BARS;
        // ph3 (1,0)
        LDAF(0, 1);
        if (pf) STGB(0, t + 2, 0);
        BARS; LGK0; MFMAQ(1, 0, bfr0);
        BARS;
        // ph4 (1,1) — no LDS reads (all operands held in regs)
        if (pf) STGB(0, t + 2, 1);
        BARS; MFMAQ(1, 1, bfr1);
        if (pf) { VMW10; } else { VMW4; }
        BARS;
        // ---- tile t+1 (buf1) ----
        // ph5 (0,0)
        LDAF(1, 0); LDB(1, 0, bfr0);
        if (pf) STGA(0, t + 2, 1);
        BARS; LGK0; MFMAQ(0, 0, bfr0);
        if (pf) { VMW10; } else { VMW2; }
        BARS;
        // ph6 (0,1)
        LDB(1, 1, bfr1);
        if (pf) STGA(1, t + 3, 0);
        BARS; LGK0; MFMAQ(0, 1, bfr1);
        if (pf) { VMW10; } else { VMW0; }
        BARS;
        // ph7 (1,0)
        LDAF(1, 1);
        if (pf) STGB(1, t + 3, 0);
        BARS; LGK0; MFMAQ(1, 0, bfr0);
        BARS;
        // ph8 (1,1)
        if (pf) STGB(1, t + 3, 1);
        BARS; MFMAQ(1, 1, bfr1);
        if (pf) { VMW10; }
        BARS;
    }

    // Epilogue: C/D layout col=lane&15, row=quad*4+reg (m89-verified).
#pragma unroll
    for (int i = 0; i < 8; i++) {
        const int row = m0 + wr * 128 + i * 16 + quad * 4;
#pragma unroll
        for (int j = 0; j < 4; j++) {
            const int col = n0 + wc * 64 + j * 16 + m16;
            const bool isv = (out_mode == 1) || (out_mode == 2 && col >= DD);
            const int cv = (out_mode == 2 && col >= DD) ? col - DD : col;
            const float bb = (out_mode == 2 && col >= DD)
                                 ? bias2[cv]
                                 : (bias ? bias[col] : 0.f);
#pragma unroll
            for (int r = 0; r < 4; r++) {
                float v = acc[i][j][r] + bb;
                if (isv) {
                    const int bb2 = (row + r) >> 11, s = (row + r) & 2047;
                    const int hh2 = cv >> 7, dd2 = cv & 127;
                    ushort* dst = (ushort*)((out_mode == 2) ? C2 : C);
                    dst[((size_t)(bb2 * HH + hh2) * DKK + dd2) * SS + s] = f2bits(v);
                } else {
                    const size_t idx = (size_t)(row + r) * Nx + cv;
                    if (res_mode == 1)      v += ((const float*)residual)[idx];
                    else if (res_mode == 2) v += bits2f(((const ushort*)residual)[idx]);
                    if (relu) v = fmaxf(v, 0.f);
                    if (c_f32) ((float*)C)[idx] = v;
                    else       ((ushort*)C)[idx] = f2bits(v);
                }
            }
        }
    }
}

// ---------------------------------------------------------------------------
// Flash attention: block = (64 q-rows, h, b), 4 waves; online softmax;
// P via LDS C->A relayout. Unchanged this round (next target).
// ---------------------------------------------------------------------------
#define SQK 144
#define SV  72
#define SP  72
__global__ __launch_bounds__(256) void attn_kernel(const bf16t* __restrict__ q,
                                                   const bf16t* __restrict__ k,
                                                   const bf16t* __restrict__ vT,
                                                   bf16t* __restrict__ o) {
    __shared__ __align__(16) ushort Qt[64 * SQK];
    __shared__ __align__(16) ushort Kt[64 * SQK];
    __shared__ __align__(16) ushort Vt[128 * SV];
    __shared__ __align__(16) ushort Pt[4][16 * SP];

    const int tid = threadIdx.x;
    const int wid = tid >> 6, lane = tid & 63;
    const int m16 = lane & 15, quad = lane >> 4;
    const int qt = blockIdx.x, h = blockIdx.y, b = blockIdx.z;
    const int q0 = qt * 64;

    const ushort* qu = (const ushort*)q;
    const ushort* ku = (const ushort*)k;
    const ushort* vu = (const ushort*)vT;

#pragma unroll
    for (int it = 0; it < 4; it++) {
        const int c0 = tid + it * 256;
        const int r = c0 >> 4, cc = (c0 & 15) * 8;
        *(uint4*)&Qt[r * SQK + cc] =
            *(const uint4*)(qu + (size_t)(b * SS + q0 + r) * DD + h * DKK + cc);
    }

    float m_r[4], l_r[4];
    floatx4 acc_o[8];
#pragma unroll
    for (int r = 0; r < 4; r++) { m_r[r] = -1e30f; l_r[r] = 0.f; }
#pragma unroll
    for (int t = 0; t < 8; t++) acc_o[t] = (floatx4){0.f, 0.f, 0.f, 0.f};

    const float scale = 0.08838834764831845f;   // 1/sqrt(128)

    for (int kt2 = 0; kt2 < SS / 64; kt2++) {
        __syncthreads();
#pragma unroll
        for (int it = 0; it < 4; it++) {
            const int c0 = tid + it * 256;
            const int r = c0 >> 4, cc = (c0 & 15) * 8;
            *(uint4*)&Kt[r * SQK + cc] =
                *(const uint4*)(ku + (size_t)(b * SS + kt2 * 64 + r) * DD + h * DKK + cc);
            const int r2 = c0 >> 3, cc2 = (c0 & 7) * 8;
            *(uint4*)&Vt[r2 * SV + cc2] =
                *(const uint4*)(vu + (size_t)((b * HH + h) * DKK + r2) * SS + kt2 * 64 + cc2);
        }
        __syncthreads();

        short8 af[4];
#pragma unroll
        for (int kk = 0; kk < 4; kk++)
            af[kk] = *(const short8*)&Qt[(wid * 16 + m16) * SQK + kk * 32 + quad * 8];
        floatx4 sacc[4];
#pragma unroll
        for (int j = 0; j < 4; j++) {
            sacc[j] = (floatx4){0.f, 0.f, 0.f, 0.f};
#pragma unroll
            for (int kk = 0; kk < 4; kk++) {
                short8 bfk = *(const short8*)&Kt[(j * 16 + m16) * SQK + kk * 32 + quad * 8];
                sacc[j] = __builtin_amdgcn_mfma_f32_16x16x32_bf16(af[kk], bfk, sacc[j], 0, 0, 0);
            }
        }
#pragma unroll
        for (int r = 0; r < 4; r++) {
            float s0 = sacc[0][r] * scale, s1 = sacc[1][r] * scale;
            float s2 = sacc[2][r] * scale, s3 = sacc[3][r] * scale;
            float mx = fmaxf(fmaxf(s0, s1), fmaxf(s2, s3));
#pragma unroll
            for (int off = 1; off < 16; off <<= 1) mx = fmaxf(mx, __shfl_xor(mx, off));
            const float mnew = fmaxf(m_r[r], mx);
            const float alpha = __expf(m_r[r] - mnew);
            m_r[r] = mnew;
            const float p0 = __expf(s0 - mnew), p1 = __expf(s1 - mnew);
            const float p2 = __expf(s2 - mnew), p3 = __expf(s3 - mnew);
            float rs = p0 + p1 + p2 + p3;
#pragma unroll
            for (int off = 1; off < 16; off <<= 1) rs += __shfl_xor(rs, off);
            l_r[r] = l_r[r] * alpha + rs;
#pragma unroll
            for (int t = 0; t < 8; t++) acc_o[t][r] *= alpha;
            const int prow = (quad * 4 + r) * SP;
            Pt[wid][prow + 0 * 16 + m16] = f2bits(p0);
            Pt[wid][prow + 1 * 16 + m16] = f2bits(p1);
            Pt[wid][prow + 2 * 16 + m16] = f2bits(p2);
            Pt[wid][prow + 3 * 16 + m16] = f2bits(p3);
        }
#pragma unroll
        for (int kk2 = 0; kk2 < 2; kk2++) {
            short8 ap = *(const short8*)&Pt[wid][m16 * SP + kk2 * 32 + quad * 8];
#pragma unroll
            for (int t = 0; t < 8; t++) {
                short8 bv = *(const short8*)&Vt[(t * 16 + m16) * SV + kk2 * 32 + quad * 8];
                acc_o[t] = __builtin_amdgcn_mfma_f32_16x16x32_bf16(ap, bv, acc_o[t], 0, 0, 0);
            }
        }
    }

    ushort* ou = (ushort*)o;
#pragma unroll
    for (int t = 0; t < 8; t++) {
#pragma unroll
        for (int r = 0; r < 4; r++) {
            const float v = acc_o[t][r] / l_r[r];
            ou[(size_t)(b * SS + q0 + wid * 16 + quad * 4 + r) * DD + h * DKK + t * 16 + m16] = f2bits(v);
        }
    }
}

// ---------------------------------------------------------------------------
// Orchestration (unchanged from r4). ws: 4 x 16 MiB slots.
// ---------------------------------------------------------------------------
extern "C" void kernel_launch(void* const* d_in, const int* in_sizes, int n_in,
                              void* d_out, int out_size, void* d_ws, size_t ws_size,
                              hipStream_t stream) {
    const float* x   = (const float*)d_in[0];
    // d_in[1] = mask (int32, all ones) — no-op in reference, skipped
    const float* wq = (const float*)d_in[2];  const float* bq = (const float*)d_in[3];
    const float* wk = (const float*)d_in[4];  const float* bk = (const float*)d_in[5];
    const float* wv = (const float*)d_in[6];  const float* bv = (const float*)d_in[7];
    const float* wo = (const float*)d_in[8];  const float* bo = (const float*)d_in[9];
    const float* w1 = (const float*)d_in[10]; const float* b1 = (const float*)d_in[11];
    const float* w2 = (const float*)d_in[12]; const float* b2 = (const float*)d_in[13];
    const float* g1 = (const float*)d_in[14]; const float* lb1 = (const float*)d_in[15];
    const float* g2 = (const float*)d_in[16]; const float* lb2 = (const float*)d_in[17];

    char* ws = (char*)d_ws;
    bf16t* S0 = (bf16t*)(ws);
    bf16t* S1 = (bf16t*)(ws + (16u << 20));
    bf16t* S2 = (bf16t*)(ws + (32u << 20));
    bf16t* S3 = (bf16t*)(ws + (48u << 20));

    bf16t* n_buf  = S0;
    bf16t* k_buf  = S1;
    bf16t* wT_buf = S2;              // wq^T (8 MiB), then wkv^T (16 MiB)
    bf16t* vT_buf = S3;
    bf16t* q_buf  = (bf16t*)d_out;   // scratch (d_out = 33.5 MB f32)
    bf16t* a_buf  = S2;              // after attn (wkvT dead)
    bf16t* woT    = S0;              // after QKV (n dead)
    bf16t* n2_buf = S0;              // after LN2 (woT dead)
    bf16t* h_buf  = S1;              // FFN half activations, 32 MiB (S1+S2)
    bf16t* wfT    = S3;              // FFN weight transposes (vT dead)

    const dim3 tb(32, 8);
    const dim3 grT(DD / 32, DD / 32);          // 2048x2048 transposes
    const dim3 gr256(DD / 256, MM / 256);      // (8, 16) for N=2048 GEMMs
    const dim3 grKV(2 * DD / 256, MM / 256);   // (16, 16) fused KV, full coverage

    // LN1: x(f32) -> n(bf16)
    ln_kernel<<<MM, 256, 0, stream>>>(x, g1, lb1, n_buf, 1);

    // Q projection first (wqT occupies S2 before wkvT overwrites it)
    wtrans_kernel<<<grT, tb, 0, stream>>>(wq, wT_buf, DD, 0, 0, DD);
    gemm256<<<gr256, 512, 0, stream>>>(n_buf, wT_buf, bq, nullptr, nullptr, 0,
                                       q_buf, nullptr, 0, DD, DD, 0, 0);

    // Fused KV: wkvT = [wk^T ; wv^T] (16 MiB in S2), one N=4096 GEMM
    wtrans_kernel<<<grT, tb, 0, stream>>>(wk, wT_buf, DD, 0, 0, DD);
    wtrans_kernel<<<grT, tb, 0, stream>>>(wv, wT_buf + (size_t)DD * DD, DD, 0, 0, DD);
    gemm256<<<grKV, 512, 0, stream>>>(n_buf, wT_buf, bk, bv, nullptr, 0,
                                      k_buf, vT_buf, 0, DD, DD, 0, 2);

    // attention -> a (S2; wkvT dead)
    attn_kernel<<<dim3(SS / 64, HH, BB), 256, 0, stream>>>(q_buf, k_buf, vT_buf, a_buf);

    // x1 = x + a @ wo + bo -> d_out (f32); residual x external f32
    wtrans_kernel<<<grT, tb, 0, stream>>>(wo, woT, DD, 0, 0, DD);
    gemm256<<<gr256, 512, 0, stream>>>(a_buf, woT, bo, nullptr, x, 1,
                                       d_out, nullptr, 1, DD, DD, 0, 0);

    // LN2: x1(f32, in d_out) -> n2
    ln_kernel<<<MM, 256, 0, stream>>>(d_out, g2, lb2, n2_buf, 1);

    // FFN in two F-halves: d_out = x1 + relu(n2@w1+b1) @ w2 + b2 (f32 in place)
    for (int hf = 0; hf < 2; hf++) {
        const int f0 = hf * FH;
        // w1Th = w1[:, f0:f0+FH]^T (bf16 [FH][D])
        wtrans_kernel<<<dim3(FH / 32, DD / 32), tb, 0, stream>>>(w1, wfT, FF, 0, f0, DD);
        // h = relu(n2 @ w1Th + b1[f0:]) (bf16 [M][FH], 32 MiB in S1+S2)
        gemm256<<<dim3(FH / 256, MM / 256), 512, 0, stream>>>(
            n2_buf, wfT, b1 + f0, nullptr, nullptr, 0, h_buf, nullptr, 0, FH, DD, 1, 0);
        // w2Th = w2[f0:f0+FH, :]^T (bf16 [D][FH])
        wtrans_kernel<<<dim3(DD / 32, FH / 32), tb, 0, stream>>>(w2, wfT, DD, f0, 0, FH);
        // d_out += h @ w2Th (+b2 on first half); residual = d_out (x1 f32), in-place
        gemm256<<<gr256, 512, 0, stream>>>(
            h_buf, wfT, hf == 0 ? b2 : nullptr, nullptr, d_out, 1,
            d_out, nullptr, 1, DD, FH, 0, 0);
    }
}

// Round 7
// 1061.676 us; speedup vs baseline: 1.3240x; 1.0835x over previous
//
#include <hip/hip_runtime.h>
#include <hip/hip_bf16.h>
#include <cmath>

// Problem constants (B,S,D,H,F fixed by the reference). Inputs f32,
// internal compute bf16 MFMA, output f32.
#define BB  2
#define SS  2048
#define DD  2048
#define HH  16
#define DKK 128      // D / H
#define FF  8192
#define FH  4096     // F / 2 (FFN split into halves)
#define MM  4096     // B * S
#define EPSL 1e-6f

typedef __attribute__((ext_vector_type(8))) short  short8;   // 8 bf16 MFMA frag
typedef __attribute__((ext_vector_type(4))) float  floatx4;  // MFMA accumulator
typedef __hip_bfloat16 bf16t;

__device__ __forceinline__ float bits2f(ushort u) {
    return __uint_as_float(((unsigned int)u) << 16);
}
__device__ __forceinline__ ushort f2bits(float f) {
    __hip_bfloat16 h = __float2bfloat16(f);
    return *reinterpret_cast<ushort*>(&h);
}

// ---------------------------------------------------------------------------
// LayerNorm (torch semantics: mean, std ddof=1, y=g*(x-m)/(std+eps)+b).
// ---------------------------------------------------------------------------
__global__ __launch_bounds__(256) void ln_kernel(const void* __restrict__ x,
                                                 const float* __restrict__ g,
                                                 const float* __restrict__ b,
                                                 bf16t* __restrict__ out,
                                                 int in_f32) {
    const int row = blockIdx.x;
    const int t = threadIdx.x;

    float v[8];
    if (in_f32) {
        const float* xr = (const float*)x + (size_t)row * DD;
        const float4 a4 = ((const float4*)xr)[2 * t];
        const float4 b4 = ((const float4*)xr)[2 * t + 1];
        v[0] = a4.x; v[1] = a4.y; v[2] = a4.z; v[3] = a4.w;
        v[4] = b4.x; v[5] = b4.y; v[6] = b4.z; v[7] = b4.w;
    } else {
        const ushort* xr = (const ushort*)x + (size_t)row * DD;
        union { uint4 u; ushort s[8]; } p;
        p.u = ((const uint4*)xr)[t];
#pragma unroll
        for (int i = 0; i < 8; i++) v[i] = bits2f(p.s[i]);
    }

    float sum = 0.f, sq = 0.f;
#pragma unroll
    for (int i = 0; i < 8; i++) { sum += v[i]; sq += v[i] * v[i]; }
#pragma unroll
    for (int off = 32; off > 0; off >>= 1) {
        sum += __shfl_down(sum, off);
        sq  += __shfl_down(sq, off);
    }
    __shared__ float ssum[4], ssq[4];
    const int wid = t >> 6, lane = t & 63;
    if (lane == 0) { ssum[wid] = sum; ssq[wid] = sq; }
    __syncthreads();
    if (t == 0) {
        float S = 0.f, Q = 0.f;
#pragma unroll
        for (int i = 0; i < 4; i++) { S += ssum[i]; Q += ssq[i]; }
        ssum[0] = S; ssq[0] = Q;
    }
    __syncthreads();
    const float S = ssum[0], Q = ssq[0];
    const float mean = S / (float)DD;
    float var = (Q - S * mean) / (float)(DD - 1);
    var = fmaxf(var, 0.f);
    const float inv = 1.0f / (sqrtf(var) + EPSL);

    const float4 ga = ((const float4*)g)[2 * t], gb = ((const float4*)g)[2 * t + 1];
    const float4 ba = ((const float4*)b)[2 * t], bb4 = ((const float4*)b)[2 * t + 1];
    const float gv[8] = {ga.x, ga.y, ga.z, ga.w, gb.x, gb.y, gb.z, gb.w};
    const float bv[8] = {ba.x, ba.y, ba.z, ba.w, bb4.x, bb4.y, bb4.z, bb4.w};

    union { uint4 u; ushort s[8]; } o;
#pragma unroll
    for (int i = 0; i < 8; i++) o.s[i] = f2bits((v[i] - mean) * inv * gv[i] + bv[i]);
    ((uint4*)((ushort*)out + (size_t)row * DD))[t] = o.u;
}

// ---------------------------------------------------------------------------
// Weight transpose + f32->bf16: out[c][r] = in[r0+r][c0+c], 32x32 tiles.
// ---------------------------------------------------------------------------
__global__ __launch_bounds__(256) void wtrans_kernel(const float* __restrict__ in,
                                                     bf16t* __restrict__ out,
                                                     int Cs, int r0, int c0, int nR) {
    __shared__ ushort tile[32][33];
    const int tx = threadIdx.x, ty = threadIdx.y;
    const int cc = blockIdx.x * 32, rr = blockIdx.y * 32;
#pragma unroll
    for (int j = 0; j < 4; j++)
        tile[ty + j * 8][tx] = f2bits(in[(size_t)(r0 + rr + ty + j * 8) * Cs + c0 + cc + tx]);
    __syncthreads();
    ushort* op = (ushort*)out;
#pragma unroll
    for (int j = 0; j < 4; j++)
        op[(size_t)(cc + ty + j * 8) * nR + rr + tx] = tile[tx][ty + j * 8];
}

// ===========================================================================
// 256x256 8-phase GEMM (r6 rework):
//  - sched_barrier(0) REMOVED (m141: order-pinning defeats the scheduler;
//    rule #18 applies only to inline-asm ds_reads, ours are compiler-visible).
//  - Swizzle (r5, verified): 16B-chunk ^ (row&7); DMA source chunk
//    (lane&7)^(lane>>3); read chunk (quad+4ks)^(m16&7).
//  - Fragment regs held across phases: 24 ds_read_b128 / K-tile / wave.
//  - Uniform 1-stage/phase; steady-state vmcnt(10); drain 10/8/4/2/0.
//  - Split-K support: blockIdx.z selects K-chunk [z*Kx, (z+1)*Kx) with
//    independent A/B row strides (Ksa/Ksb).
//  - out_mode: 0 plain (res_mode/relu/c_f32), 3 fused QKV (col>>11: 0=Q
//    plain->CQ+biasQ, 1=K plain->C+bias, 2=V-transposed->C2+bias2),
//    4 atomicAdd f32 into C (+bias when z==0). Region branch block-uniform.
// ===========================================================================
template<int IB>   // IB=6: A (64-row interleave); IB=5: B (32-row interleave)
__device__ __forceinline__ void stage_half(const ushort* __restrict__ g, int Ks,
                                           ushort* lds, int h, int wid, int lane) {
#pragma unroll
    for (int l = 0; l < 2; l++) {
        const int c = wid * 2 + l;            // chunk 0..15, 8 rows x 128 B each
        const int rs = (IB == 6) ? (((c & 8) ? 128 : 0) + h * 64 + (c & 7) * 8)
                                 : ((c >> 2) * 64 + h * 32 + (c & 3) * 8);
        const int row = rs + (lane >> 3);
        const int csrc = (lane & 7) ^ (lane >> 3);   // pre-swizzled source chunk
        const ushort* gp = g + (size_t)row * Ks + csrc * 8;
        __builtin_amdgcn_global_load_lds(
            (const __attribute__((address_space(1))) void*)gp,
            (__attribute__((address_space(3))) void*)(lds + rs * 64), 16, 0, 0);
    }
}

#define VMW10 asm volatile("s_waitcnt vmcnt(10)" ::: "memory")
#define VMW8  asm volatile("s_waitcnt vmcnt(8)" ::: "memory")
#define VMW4  asm volatile("s_waitcnt vmcnt(4)" ::: "memory")
#define VMW2  asm volatile("s_waitcnt vmcnt(2)" ::: "memory")
#define VMW0  asm volatile("s_waitcnt vmcnt(0)" ::: "memory")
#define LGK0  asm volatile("s_waitcnt lgkmcnt(0)" ::: "memory")
#define BARS  __builtin_amdgcn_s_barrier()

#define STGA(buf, kt, h) stage_half<6>(gAu + (size_t)(kt) * 64, Ksa, &LAf[(buf) * (256 * 64)], (h), wid, lane)
#define STGB(buf, kt, h) stage_half<5>(gBu + (size_t)(kt) * 64, Ksb, &LBf[(buf) * (256 * 64)], (h), wid, lane)

#define LDAF(BUF, MH)                                                     \
    do { const ushort* Lp = &LAf[(BUF) * (256 * 64)];                     \
        _Pragma("unroll") for (int i = 0; i < 4; i++) {                   \
            const int rr = (arow0 + ((MH) * 4 + i) * 16) * 64;            \
            af[i][0] = *(const short8*)&Lp[rr + swz0];                    \
            af[i][1] = *(const short8*)&Lp[rr + swz1];                    \
        } } while (0)

#define LDB(BUF, NH, DST)                                                 \
    do { const ushort* Lp = &LBf[(BUF) * (256 * 64)];                     \
        _Pragma("unroll") for (int j = 0; j < 2; j++) {                   \
            const int rr = (brow0 + ((NH) * 2 + j) * 16) * 64;            \
            DST[j][0] = *(const short8*)&Lp[rr + swz0];                   \
            DST[j][1] = *(const short8*)&Lp[rr + swz1];                   \
        } } while (0)

#define MFMAQ(MH, NH, BSRC)                                               \
    do { __builtin_amdgcn_s_setprio(1);                                   \
        _Pragma("unroll") for (int i = 0; i < 4; i++)                     \
        _Pragma("unroll") for (int j = 0; j < 2; j++) {                   \
            acc[(MH) * 4 + i][(NH) * 2 + j] =                             \
                __builtin_amdgcn_mfma_f32_16x16x32_bf16(                  \
                    af[i][0], BSRC[j][0], acc[(MH) * 4 + i][(NH) * 2 + j], 0, 0, 0); \
            acc[(MH) * 4 + i][(NH) * 2 + j] =                             \
                __builtin_amdgcn_mfma_f32_16x16x32_bf16(                  \
                    af[i][1], BSRC[j][1], acc[(MH) * 4 + i][(NH) * 2 + j], 0, 0, 0); \
        }                                                                 \
        __builtin_amdgcn_s_setprio(0); } while (0)

__global__ __launch_bounds__(512, 2) void gemm256(const bf16t* __restrict__ A,
                                                  const bf16t* __restrict__ BT,
                                                  const float* __restrict__ bias,
                                                  const float* __restrict__ bias2,
                                                  const float* __restrict__ biasQ,
                                                  const void* __restrict__ residual, int res_mode,
                                                  void* __restrict__ C, void* __restrict__ C2,
                                                  void* __restrict__ CQ,
                                                  int c_f32, int Nx, int Kx, int Ksa, int Ksb,
                                                  int relu, int out_mode) {
    __shared__ __align__(16) ushort LAf[2 * 256 * 64];   // 64 KiB
    __shared__ __align__(16) ushort LBf[2 * 256 * 64];   // 64 KiB

    const int tid = threadIdx.x;
    const int wid = tid >> 6, lane = tid & 63;
    const int m16 = lane & 15, quad = lane >> 4;
    const int wr = wid >> 2, wc = wid & 3;            // 2 x 4 wave grid
    const int zed = blockIdx.z;

    // Bijective XCD-aware block swizzle (nwg % 8 == 0 for all our grids)
    const int gx = gridDim.x;
    const int nwg = gx * gridDim.y;
    const int orig = blockIdx.y * gx + blockIdx.x;
    const int bid = (orig & 7) * (nwg >> 3) + (orig >> 3);
    const int m0 = (bid / gx) * 256, n0 = (bid % gx) * 256;

    const ushort* gAu = (const ushort*)A + (size_t)m0 * Ksa + (size_t)zed * Kx;
    const ushort* gBu = (const ushort*)BT + (size_t)n0 * Ksb + (size_t)zed * Kx;

    floatx4 acc[8][4];
#pragma unroll
    for (int i = 0; i < 8; i++)
#pragma unroll
        for (int j = 0; j < 4; j++) acc[i][j] = (floatx4){0.f, 0.f, 0.f, 0.f};

    // Swizzled per-lane k-chunk offsets: chunk (quad+4ks) ^ (row&7).
    const int sw = m16 & 7;
    const int swz0 = (quad ^ sw) << 3;
    const int swz1 = ((quad + 4) ^ sw) << 3;
    const int arow0 = wr * 128 + m16;
    const int brow0 = wc * 64 + m16;

    const int nk = Kx / 64;

    // Prologue: o1..o7 = A0h0,B0h0,B0h1,A0h1,A1h0,B1h0,B1h1 (A1h1 staged ph1)
    STGA(0, 0, 0); STGB(0, 0, 0); STGB(0, 0, 1); STGA(0, 0, 1);
    STGA(1, 1, 0); STGB(1, 1, 0); STGB(1, 1, 1);
    VMW10;
    BARS;

    short8 af[4][2], bfr0[2][2], bfr1[2][2];

    for (int t = 0; t < nk; t += 2) {
        const bool pf = (t + 2 < nk);
        // ---- tile t (buf0) ----
        // ph1 (0,0)
        LDAF(0, 0); LDB(0, 0, bfr0);
        STGA(1, t + 1, 1);                       // A(b)h1, read ph7
        BARS; LGK0; MFMAQ(0, 0, bfr0);
        VMW10; BARS;
        // ph2 (0,1)
        LDB(0, 1, bfr1);
        if (pf) STGA(0, t + 2, 0);
        BARS; LGK0; MFMAQ(0, 1, bfr1);
        if (pf) { VMW10; } else { VMW8; }
        BARS;
        // ph3 (1,0)
        LDAF(0, 1);
        if (pf) STGB(0, t + 2, 0);
        BARS; LGK0; MFMAQ(1, 0, bfr0);
        BARS;
        // ph4 (1,1) — no LDS reads (all operands held in regs)
        if (pf) STGB(0, t + 2, 1);
        BARS; MFMAQ(1, 1, bfr1);
        if (pf) { VMW10; } else { VMW4; }
        BARS;
        // ---- tile t+1 (buf1) ----
        // ph5 (0,0)
        LDAF(1, 0); LDB(1, 0, bfr0);
        if (pf) STGA(0, t + 2, 1);
        BARS; LGK0; MFMAQ(0, 0, bfr0);
        if (pf) { VMW10; } else { VMW2; }
        BARS;
        // ph6 (0,1)
        LDB(1, 1, bfr1);
        if (pf) STGA(1, t + 3, 0);
        BARS; LGK0; MFMAQ(0, 1, bfr1);
        if (pf) { VMW10; } else { VMW0; }
        BARS;
        // ph7 (1,0)
        LDAF(1, 1);
        if (pf) STGB(1, t + 3, 0);
        BARS; LGK0; MFMAQ(1, 0, bfr0);
        BARS;
        // ph8 (1,1)
        if (pf) STGB(1, t + 3, 1);
        BARS; MFMAQ(1, 1, bfr1);
        if (pf) { VMW10; }
        BARS;
    }

    // Epilogue: C/D layout col=lane&15, row=quad*4+reg (m89-verified).
#pragma unroll
    for (int i = 0; i < 8; i++) {
        const int row = m0 + wr * 128 + i * 16 + quad * 4;
#pragma unroll
        for (int j = 0; j < 4; j++) {
            const int col = n0 + wc * 64 + j * 16 + m16;
            if (out_mode == 3) {
                // fused QKV: block-uniform region by col>>11
                const int reg3 = col >> 11, cv = col & 2047;
                const float bb = (reg3 == 0) ? biasQ[cv]
                               : (reg3 == 1) ? bias[cv] : bias2[cv];
#pragma unroll
                for (int r = 0; r < 4; r++) {
                    const float v = acc[i][j][r] + bb;
                    if (reg3 == 2) {
                        const int bb2 = (row + r) >> 11, s = (row + r) & 2047;
                        ((ushort*)C2)[((size_t)(bb2 * HH + (cv >> 7)) * DKK + (cv & 127)) * SS + s] = f2bits(v);
                    } else {
                        ushort* dst = (ushort*)((reg3 == 0) ? CQ : C);
                        dst[(size_t)(row + r) * DD + cv] = f2bits(v);
                    }
                }
            } else if (out_mode == 4) {
                const float bb = (bias && zed == 0) ? bias[col] : 0.f;
#pragma unroll
                for (int r = 0; r < 4; r++)
                    atomicAdd((float*)C + (size_t)(row + r) * Nx + col, acc[i][j][r] + bb);
            } else {
                const float bb = bias ? bias[col] : 0.f;
#pragma unroll
                for (int r = 0; r < 4; r++) {
                    float v = acc[i][j][r] + bb;
                    const size_t idx = (size_t)(row + r) * Nx + col;
                    if (res_mode == 1)      v += ((const float*)residual)[idx];
                    else if (res_mode == 2) v += bits2f(((const ushort*)residual)[idx]);
                    if (relu) v = fmaxf(v, 0.f);
                    if (c_f32) ((float*)C)[idx] = v;
                    else       ((ushort*)C)[idx] = f2bits(v);
                }
            }
        }
    }
}

// ---------------------------------------------------------------------------
// Flash attention: block = (64 q-rows, h, b), 4 waves; online softmax.
// r6: Q fragments hoisted out of the KV loop; T13 defer-max (skip rescale
// when group max grows <= 8; P bounded by e^8, bf16-safe; group-uniform).
// ---------------------------------------------------------------------------
#define SQK 144
#define SV  72
#define SP  72
__global__ __launch_bounds__(256) void attn_kernel(const bf16t* __restrict__ q,
                                                   const bf16t* __restrict__ k,
                                                   const bf16t* __restrict__ vT,
                                                   bf16t* __restrict__ o) {
    __shared__ __align__(16) ushort Qt[64 * SQK];
    __shared__ __align__(16) ushort Kt[64 * SQK];
    __shared__ __align__(16) ushort Vt[128 * SV];
    __shared__ __align__(16) ushort Pt[4][16 * SP];

    const int tid = threadIdx.x;
    const int wid = tid >> 6, lane = tid & 63;
    const int m16 = lane & 15, quad = lane >> 4;
    const int qt = blockIdx.x, h = blockIdx.y, b = blockIdx.z;
    const int q0 = qt * 64;

    const ushort* qu = (const ushort*)q;
    const ushort* ku = (const ushort*)k;
    const ushort* vu = (const ushort*)vT;

#pragma unroll
    for (int it = 0; it < 4; it++) {
        const int c0 = tid + it * 256;
        const int r = c0 >> 4, cc = (c0 & 15) * 8;
        *(uint4*)&Qt[r * SQK + cc] =
            *(const uint4*)(qu + (size_t)(b * SS + q0 + r) * DD + h * DKK + cc);
    }
    __syncthreads();

    // Q fragments: loop-invariant, hoisted (Qt never overwritten)
    short8 afq[4];
#pragma unroll
    for (int kk = 0; kk < 4; kk++)
        afq[kk] = *(const short8*)&Qt[(wid * 16 + m16) * SQK + kk * 32 + quad * 8];

    float m_r[4], l_r[4];
    floatx4 acc_o[8];
#pragma unroll
    for (int r = 0; r < 4; r++) { m_r[r] = -1e30f; l_r[r] = 0.f; }
#pragma unroll
    for (int t = 0; t < 8; t++) acc_o[t] = (floatx4){0.f, 0.f, 0.f, 0.f};

    const float scale = 0.08838834764831845f;   // 1/sqrt(128)

    for (int kt2 = 0; kt2 < SS / 64; kt2++) {
        __syncthreads();
#pragma unroll
        for (int it = 0; it < 4; it++) {
            const int c0 = tid + it * 256;
            const int r = c0 >> 4, cc = (c0 & 15) * 8;
            *(uint4*)&Kt[r * SQK + cc] =
                *(const uint4*)(ku + (size_t)(b * SS + kt2 * 64 + r) * DD + h * DKK + cc);
            const int r2 = c0 >> 3, cc2 = (c0 & 7) * 8;
            *(uint4*)&Vt[r2 * SV + cc2] =
                *(const uint4*)(vu + (size_t)((b * HH + h) * DKK + r2) * SS + kt2 * 64 + cc2);
        }
        __syncthreads();

        floatx4 sacc[4];
#pragma unroll
        for (int j = 0; j < 4; j++) {
            sacc[j] = (floatx4){0.f, 0.f, 0.f, 0.f};
#pragma unroll
            for (int kk = 0; kk < 4; kk++) {
                short8 bfk = *(const short8*)&Kt[(j * 16 + m16) * SQK + kk * 32 + quad * 8];
                sacc[j] = __builtin_amdgcn_mfma_f32_16x16x32_bf16(afq[kk], bfk, sacc[j], 0, 0, 0);
            }
        }
#pragma unroll
        for (int r = 0; r < 4; r++) {
            float s0 = sacc[0][r] * scale, s1 = sacc[1][r] * scale;
            float s2 = sacc[2][r] * scale, s3 = sacc[3][r] * scale;
            float mx = fmaxf(fmaxf(s0, s1), fmaxf(s2, s3));
#pragma unroll
            for (int off = 1; off < 16; off <<= 1) mx = fmaxf(mx, __shfl_xor(mx, off));
            // T13 defer-max: rescale only on significant growth (>8).
            // Group-uniform branch (mx, m_r uniform within 16-lane group).
            if (mx > m_r[r] + 8.f) {
                const float al = __expf(m_r[r] - mx);
                m_r[r] = mx;
                l_r[r] *= al;
#pragma unroll
                for (int t = 0; t < 8; t++) acc_o[t][r] *= al;
            }
            const float mm = m_r[r];
            const float p0 = __expf(s0 - mm), p1 = __expf(s1 - mm);
            const float p2 = __expf(s2 - mm), p3 = __expf(s3 - mm);
            float rs = p0 + p1 + p2 + p3;
#pragma unroll
            for (int off = 1; off < 16; off <<= 1) rs += __shfl_xor(rs, off);
            l_r[r] += rs;
            const int prow = (quad * 4 + r) * SP;
            Pt[wid][prow + 0 * 16 + m16] = f2bits(p0);
            Pt[wid][prow + 1 * 16 + m16] = f2bits(p1);
            Pt[wid][prow + 2 * 16 + m16] = f2bits(p2);
            Pt[wid][prow + 3 * 16 + m16] = f2bits(p3);
        }
#pragma unroll
        for (int kk2 = 0; kk2 < 2; kk2++) {
            short8 ap = *(const short8*)&Pt[wid][m16 * SP + kk2 * 32 + quad * 8];
#pragma unroll
            for (int t = 0; t < 8; t++) {
                short8 bv = *(const short8*)&Vt[(t * 16 + m16) * SV + kk2 * 32 + quad * 8];
                acc_o[t] = __builtin_amdgcn_mfma_f32_16x16x32_bf16(ap, bv, acc_o[t], 0, 0, 0);
            }
        }
    }

    ushort* ou = (ushort*)o;
#pragma unroll
    for (int t = 0; t < 8; t++) {
#pragma unroll
        for (int r = 0; r < 4; r++) {
            const float v = acc_o[t][r] / l_r[r];
            ou[(size_t)(b * SS + q0 + wid * 16 + quad * 4 + r) * DD + h * DKK + t * 16 + m16] = f2bits(v);
        }
    }
}

// ---------------------------------------------------------------------------
// Orchestration (r6 re-layout; all lifetimes hand-verified):
//   S0 (ws+0..16M):   n -> a (after QKV) -> n2 (after O-proj)
//   ws+16..40M:       wqkvT (24M) -> woT (8M) -> w1Th/w2Th (16M, FFN)
//   ws+40..56M:       k
//   ws+32..64M:       h (32M, FFN; wqkvT/k dead by then)
//   d_out (32M):      q (bf16, 0..16M) + vT (bf16, 16..32M) -> x1 (f32) -> out
// ---------------------------------------------------------------------------
extern "C" void kernel_launch(void* const* d_in, const int* in_sizes, int n_in,
                              void* d_out, int out_size, void* d_ws, size_t ws_size,
                              hipStream_t stream) {
    const float* x   = (const float*)d_in[0];
    // d_in[1] = mask (int32, all ones) — no-op in reference, skipped
    const float* wq = (const float*)d_in[2];  const float* bq = (const float*)d_in[3];
    const float* wk = (const float*)d_in[4];  const float* bk = (const float*)d_in[5];
    const float* wv = (const float*)d_in[6];  const float* bv = (const float*)d_in[7];
    const float* wo = (const float*)d_in[8];  const float* bo = (const float*)d_in[9];
    const float* w1 = (const float*)d_in[10]; const float* b1 = (const float*)d_in[11];
    const float* w2 = (const float*)d_in[12]; const float* b2 = (const float*)d_in[13];
    const float* g1 = (const float*)d_in[14]; const float* lb1 = (const float*)d_in[15];
    const float* g2 = (const float*)d_in[16]; const float* lb2 = (const float*)d_in[17];

    char* ws = (char*)d_ws;
    bf16t* n_buf  = (bf16t*)(ws);                      // 16 MiB
    bf16t* wqkvT  = (bf16t*)(ws + (16u << 20));        // 24 MiB
    bf16t* k_buf  = (bf16t*)(ws + (40u << 20));        // 16 MiB
    bf16t* q_buf  = (bf16t*)d_out;                     // 16 MiB (scratch)
    bf16t* vT_buf = (bf16t*)((char*)d_out + (16u << 20));  // 16 MiB (scratch)
    bf16t* a_buf  = (bf16t*)(ws);                      // after QKV (n dead)
    bf16t* woT    = (bf16t*)(ws + (16u << 20));        // after QKV (wqkvT dead)
    bf16t* n2_buf = (bf16t*)(ws);                      // after O-proj (a dead)
    bf16t* wfT    = (bf16t*)(ws + (16u << 20));        // FFN weight T (16 MiB)
    bf16t* h_buf  = (bf16t*)(ws + (32u << 20));        // 32 MiB (k dead)

    const dim3 tb(32, 8);
    const dim3 grT(DD / 32, DD / 32);            // 2048x2048 transposes
    const dim3 grO(DD / 256, MM / 256);          // (8, 16) O-proj
    const dim3 grQKV(3 * DD / 256, MM / 256);    // (24, 16) fused QKV
    const dim3 grF1(FH / 256, MM / 256);         // (16, 16) FFN1 half
    const dim3 grF2(DD / 256, MM / 256, 2);      // (8, 16, 2) FFN2 split-K

    // LN1: x(f32) -> n(bf16)
    ln_kernel<<<MM, 256, 0, stream>>>(x, g1, lb1, n_buf, 1);

    // wqkvT = [wq^T ; wk^T ; wv^T] (24 MiB), single N=6144 GEMM (384 wg)
    wtrans_kernel<<<grT, tb, 0, stream>>>(wq, wqkvT, DD, 0, 0, DD);
    wtrans_kernel<<<grT, tb, 0, stream>>>(wk, wqkvT + (size_t)DD * DD, DD, 0, 0, DD);
    wtrans_kernel<<<grT, tb, 0, stream>>>(wv, wqkvT + 2 * (size_t)DD * DD, DD, 0, 0, DD);
    gemm256<<<grQKV, 512, 0, stream>>>(n_buf, wqkvT, bk, bv, bq, nullptr, 0,
                                       k_buf, vT_buf, q_buf, 0, DD, DD, DD, DD, 0, 3);

    // woT (region free after QKV GEMM; stream-ordered)
    wtrans_kernel<<<grT, tb, 0, stream>>>(wo, woT, DD, 0, 0, DD);

    // attention -> a (S0; n dead)
    attn_kernel<<<dim3(SS / 64, HH, BB), 256, 0, stream>>>(q_buf, k_buf, vT_buf, a_buf);

    // x1 = x + a @ wo + bo -> d_out (f32; q/vT dead)
    gemm256<<<grO, 512, 0, stream>>>(a_buf, woT, bo, nullptr, nullptr, x, 1,
                                     d_out, nullptr, nullptr, 1, DD, DD, DD, DD, 0, 0);

    // LN2: x1(f32, in d_out) -> n2 (S0; a dead)
    ln_kernel<<<MM, 256, 0, stream>>>(d_out, g2, lb2, n2_buf, 1);

    // FFN in two F-halves; FFN2 split-K z=2 with f32 atomicAdd into d_out
    // (d_out already holds x1; b2 added once by z==0 blocks of half 0).
    for (int hf = 0; hf < 2; hf++) {
        const int f0 = hf * FH;
        // w1Th = w1[:, f0:f0+FH]^T (bf16 [FH][D], 16 MiB)
        wtrans_kernel<<<dim3(FH / 32, DD / 32), tb, 0, stream>>>(w1, wfT, FF, 0, f0, DD);
        // h = relu(n2 @ w1Th + b1[f0:]) (bf16 [M][FH], 32 MiB)
        gemm256<<<grF1, 512, 0, stream>>>(n2_buf, wfT, b1 + f0, nullptr, nullptr,
                                          nullptr, 0, h_buf, nullptr, nullptr,
                                          0, FH, DD, DD, DD, 1, 0);
        // w2Th = w2[f0:f0+FH, :]^T (bf16 [D][FH], 16 MiB)
        wtrans_kernel<<<dim3(DD / 32, FH / 32), tb, 0, stream>>>(w2, wfT, DD, f0, 0, FH);
        // d_out += h @ w2Th (+b2 once); split-K z=2, K=2048 each, 256 wg
        gemm256<<<grF2, 512, 0, stream>>>(h_buf, wfT, hf == 0 ? b2 : nullptr,
                                          nullptr, nullptr, nullptr, 0,
                                          d_out, nullptr, nullptr,
                                          1, DD, DD, FH, FH, 0, 4);
    }
}

// Round 10
// 1047.183 us; speedup vs baseline: 1.3423x; 1.0138x over previous
//
#include <hip/hip_runtime.h>
#include <hip/hip_bf16.h>
#include <cmath>

// Problem constants (B,S,D,H,F fixed by the reference). Inputs f32,
// internal compute bf16 MFMA, output f32.
#define BB  2
#define SS  2048
#define DD  2048
#define HH  16
#define DKK 128      // D / H
#define FF  8192
#define FH  4096     // F / 2 (FFN split into halves)
#define MM  4096     // B * S
#define EPSL 1e-6f

typedef __attribute__((ext_vector_type(8))) short  short8;   // 8 bf16 MFMA frag
typedef __attribute__((ext_vector_type(4))) float  floatx4;  // MFMA accumulator
typedef __hip_bfloat16 bf16t;

__device__ __forceinline__ float bits2f(ushort u) {
    return __uint_as_float(((unsigned int)u) << 16);
}
__device__ __forceinline__ ushort f2bits(float f) {
    __hip_bfloat16 h = __float2bfloat16(f);
    return *reinterpret_cast<ushort*>(&h);
}

// ---------------------------------------------------------------------------
// LayerNorm (torch semantics: mean, std ddof=1, y=g*(x-m)/(std+eps)+b).
// ---------------------------------------------------------------------------
__global__ __launch_bounds__(256) void ln_kernel(const void* __restrict__ x,
                                                 const float* __restrict__ g,
                                                 const float* __restrict__ b,
                                                 bf16t* __restrict__ out,
                                                 int in_f32) {
    const int row = blockIdx.x;
    const int t = threadIdx.x;

    float v[8];
    if (in_f32) {
        const float* xr = (const float*)x + (size_t)row * DD;
        const float4 a4 = ((const float4*)xr)[2 * t];
        const float4 b4 = ((const float4*)xr)[2 * t + 1];
        v[0] = a4.x; v[1] = a4.y; v[2] = a4.z; v[3] = a4.w;
        v[4] = b4.x; v[5] = b4.y; v[6] = b4.z; v[7] = b4.w;
    } else {
        const ushort* xr = (const ushort*)x + (size_t)row * DD;
        union { uint4 u; ushort s[8]; } p;
        p.u = ((const uint4*)xr)[t];
#pragma unroll
        for (int i = 0; i < 8; i++) v[i] = bits2f(p.s[i]);
    }

    float sum = 0.f, sq = 0.f;
#pragma unroll
    for (int i = 0; i < 8; i++) { sum += v[i]; sq += v[i] * v[i]; }
#pragma unroll
    for (int off = 32; off > 0; off >>= 1) {
        sum += __shfl_down(sum, off);
        sq  += __shfl_down(sq, off);
    }
    __shared__ float ssum[4], ssq[4];
    const int wid = t >> 6, lane = t & 63;
    if (lane == 0) { ssum[wid] = sum; ssq[wid] = sq; }
    __syncthreads();
    if (t == 0) {
        float S = 0.f, Q = 0.f;
#pragma unroll
        for (int i = 0; i < 4; i++) { S += ssum[i]; Q += ssq[i]; }
        ssum[0] = S; ssq[0] = Q;
    }
    __syncthreads();
    const float S = ssum[0], Q = ssq[0];
    const float mean = S / (float)DD;
    float var = (Q - S * mean) / (float)(DD - 1);
    var = fmaxf(var, 0.f);
    const float inv = 1.0f / (sqrtf(var) + EPSL);

    const float4 ga = ((const float4*)g)[2 * t], gb = ((const float4*)g)[2 * t + 1];
    const float4 ba = ((const float4*)b)[2 * t], bb4 = ((const float4*)b)[2 * t + 1];
    const float gv[8] = {ga.x, ga.y, ga.z, ga.w, gb.x, gb.y, gb.z, gb.w};
    const float bv[8] = {ba.x, ba.y, ba.z, ba.w, bb4.x, bb4.y, bb4.z, bb4.w};

    union { uint4 u; ushort s[8]; } o;
#pragma unroll
    for (int i = 0; i < 8; i++) o.s[i] = f2bits((v[i] - mean) * inv * gv[i] + bv[i]);
    ((uint4*)((ushort*)out + (size_t)row * DD))[t] = o.u;
}

// ---------------------------------------------------------------------------
// Weight transpose + f32->bf16: out[c][r] = in[r0+r][c0+c], 32x32 tiles.
// ---------------------------------------------------------------------------
__global__ __launch_bounds__(256) void wtrans_kernel(const float* __restrict__ in,
                                                     bf16t* __restrict__ out,
                                                     int Cs, int r0, int c0, int nR) {
    __shared__ ushort tile[32][33];
    const int tx = threadIdx.x, ty = threadIdx.y;
    const int cc = blockIdx.x * 32, rr = blockIdx.y * 32;
#pragma unroll
    for (int j = 0; j < 4; j++)
        tile[ty + j * 8][tx] = f2bits(in[(size_t)(r0 + rr + ty + j * 8) * Cs + c0 + cc + tx]);
    __syncthreads();
    ushort* op = (ushort*)out;
#pragma unroll
    for (int j = 0; j < 4; j++)
        op[(size_t)(cc + ty + j * 8) * nR + rr + tx] = tile[tx][ty + j * 8];
}

// ===========================================================================
// 256x256 8-phase GEMM (unchanged from r6/r7 — measured improvement; no
// gemm counters visible, so no blind churn).
// ===========================================================================
template<int IB>   // IB=6: A (64-row interleave); IB=5: B (32-row interleave)
__device__ __forceinline__ void stage_half(const ushort* __restrict__ g, int Ks,
                                           ushort* lds, int h, int wid, int lane) {
#pragma unroll
    for (int l = 0; l < 2; l++) {
        const int c = wid * 2 + l;            // chunk 0..15, 8 rows x 128 B each
        const int rs = (IB == 6) ? (((c & 8) ? 128 : 0) + h * 64 + (c & 7) * 8)
                                 : ((c >> 2) * 64 + h * 32 + (c & 3) * 8);
        const int row = rs + (lane >> 3);
        const int csrc = (lane & 7) ^ (lane >> 3);   // pre-swizzled source chunk
        const ushort* gp = g + (size_t)row * Ks + csrc * 8;
        __builtin_amdgcn_global_load_lds(
            (const __attribute__((address_space(1))) void*)gp,
            (__attribute__((address_space(3))) void*)(lds + rs * 64), 16, 0, 0);
    }
}

#define VMW10 asm volatile("s_waitcnt vmcnt(10)" ::: "memory")
#define VMW8  asm volatile("s_waitcnt vmcnt(8)" ::: "memory")
#define VMW4  asm volatile("s_waitcnt vmcnt(4)" ::: "memory")
#define VMW2  asm volatile("s_waitcnt vmcnt(2)" ::: "memory")
#define VMW0  asm volatile("s_waitcnt vmcnt(0)" ::: "memory")
#define LGK0  asm volatile("s_waitcnt lgkmcnt(0)" ::: "memory")
#define BARS  __builtin_amdgcn_s_barrier()

#define STGA(buf, kt, h) stage_half<6>(gAu + (size_t)(kt) * 64, Ksa, &LAf[(buf) * (256 * 64)], (h), wid, lane)
#define STGB(buf, kt, h) stage_half<5>(gBu + (size_t)(kt) * 64, Ksb, &LBf[(buf) * (256 * 64)], (h), wid, lane)

#define LDAF(BUF, MH)                                                     \
    do { const ushort* Lp = &LAf[(BUF) * (256 * 64)];                     \
        _Pragma("unroll") for (int i = 0; i < 4; i++) {                   \
            const int rr = (arow0 + ((MH) * 4 + i) * 16) * 64;            \
            af[i][0] = *(const short8*)&Lp[rr + swz0];                    \
            af[i][1] = *(const short8*)&Lp[rr + swz1];                    \
        } } while (0)

#define LDB(BUF, NH, DST)                                                 \
    do { const ushort* Lp = &LBf[(BUF) * (256 * 64)];                     \
        _Pragma("unroll") for (int j = 0; j < 2; j++) {                   \
            const int rr = (brow0 + ((NH) * 2 + j) * 16) * 64;            \
            DST[j][0] = *(const short8*)&Lp[rr + swz0];                   \
            DST[j][1] = *(const short8*)&Lp[rr + swz1];                   \
        } } while (0)

#define MFMAQ(MH, NH, BSRC)                                               \
    do { __builtin_amdgcn_s_setprio(1);                                   \
        _Pragma("unroll") for (int i = 0; i < 4; i++)                     \
        _Pragma("unroll") for (int j = 0; j < 2; j++) {                   \
            acc[(MH) * 4 + i][(NH) * 2 + j] =                             \
                __builtin_amdgcn_mfma_f32_16x16x32_bf16(                  \
                    af[i][0], BSRC[j][0], acc[(MH) * 4 + i][(NH) * 2 + j], 0, 0, 0); \
            acc[(MH) * 4 + i][(NH) * 2 + j] =                             \
                __builtin_amdgcn_mfma_f32_16x16x32_bf16(                  \
                    af[i][1], BSRC[j][1], acc[(MH) * 4 + i][(NH) * 2 + j], 0, 0, 0); \
        }                                                                 \
        __builtin_amdgcn_s_setprio(0); } while (0)

__global__ __launch_bounds__(512, 2) void gemm256(const bf16t* __restrict__ A,
                                                  const bf16t* __restrict__ BT,
                                                  const float* __restrict__ bias,
                                                  const float* __restrict__ bias2,
                                                  const float* __restrict__ biasQ,
                                                  const void* __restrict__ residual, int res_mode,
                                                  void* __restrict__ C, void* __restrict__ C2,
                                                  void* __restrict__ CQ,
                                                  int c_f32, int Nx, int Kx, int Ksa, int Ksb,
                                                  int relu, int out_mode) {
    __shared__ __align__(16) ushort LAf[2 * 256 * 64];   // 64 KiB
    __shared__ __align__(16) ushort LBf[2 * 256 * 64];   // 64 KiB

    const int tid = threadIdx.x;
    const int wid = tid >> 6, lane = tid & 63;
    const int m16 = lane & 15, quad = lane >> 4;
    const int wr = wid >> 2, wc = wid & 3;            // 2 x 4 wave grid
    const int zed = blockIdx.z;

    // Bijective XCD-aware block swizzle (nwg % 8 == 0 for all our grids)
    const int gx = gridDim.x;
    const int nwg = gx * gridDim.y;
    const int orig = blockIdx.y * gx + blockIdx.x;
    const int bid = (orig & 7) * (nwg >> 3) + (orig >> 3);
    const int m0 = (bid / gx) * 256, n0 = (bid % gx) * 256;

    const ushort* gAu = (const ushort*)A + (size_t)m0 * Ksa + (size_t)zed * Kx;
    const ushort* gBu = (const ushort*)BT + (size_t)n0 * Ksb + (size_t)zed * Kx;

    floatx4 acc[8][4];
#pragma unroll
    for (int i = 0; i < 8; i++)
#pragma unroll
        for (int j = 0; j < 4; j++) acc[i][j] = (floatx4){0.f, 0.f, 0.f, 0.f};

    // Swizzled per-lane k-chunk offsets: chunk (quad+4ks) ^ (row&7).
    const int sw = m16 & 7;
    const int swz0 = (quad ^ sw) << 3;
    const int swz1 = ((quad + 4) ^ sw) << 3;
    const int arow0 = wr * 128 + m16;
    const int brow0 = wc * 64 + m16;

    const int nk = Kx / 64;

    // Prologue: o1..o7 = A0h0,B0h0,B0h1,A0h1,A1h0,B1h0,B1h1 (A1h1 staged ph1)
    STGA(0, 0, 0); STGB(0, 0, 0); STGB(0, 0, 1); STGA(0, 0, 1);
    STGA(1, 1, 0); STGB(1, 1, 0); STGB(1, 1, 1);
    VMW10;
    BARS;

    short8 af[4][2], bfr0[2][2], bfr1[2][2];

    for (int t = 0; t < nk; t += 2) {
        const bool pf = (t + 2 < nk);
        // ---- tile t (buf0) ----
        // ph1 (0,0)
        LDAF(0, 0); LDB(0, 0, bfr0);
        STGA(1, t + 1, 1);                       // A(b)h1, read ph7
        BARS; LGK0; MFMAQ(0, 0, bfr0);
        VMW10; BARS;
        // ph2 (0,1)
        LDB(0, 1, bfr1);
        if (pf) STGA(0, t + 2, 0);
        BARS; LGK0; MFMAQ(0, 1, bfr1);
        if (pf) { VMW10; } else { VMW8; }
        BARS;
        // ph3 (1,0)
        LDAF(0, 1);
        if (pf) STGB(0, t + 2, 0);
        BARS; LGK0; MFMAQ(1, 0, bfr0);
        BARS;
        // ph4 (1,1) — no LDS reads (all operands held in regs)
        if (pf) STGB(0, t + 2, 1);
        BARS; MFMAQ(1, 1, bfr1);
        if (pf) { VMW10; } else { VMW4; }
        BARS;
        // ---- tile t+1 (buf1) ----
        // ph5 (0,0)
        LDAF(1, 0); LDB(1, 0, bfr0);
        if (pf) STGA(0, t + 2, 1);
        BARS; LGK0; MFMAQ(0, 0, bfr0);
        if (pf) { VMW10; } else { VMW2; }
        BARS;
        // ph6 (0,1)
        LDB(1, 1, bfr1);
        if (pf) STGA(1, t + 3, 0);
        BARS; LGK0; MFMAQ(0, 1, bfr1);
        if (pf) { VMW10; } else { VMW0; }
        BARS;
        // ph7 (1,0)
        LDAF(1, 1);
        if (pf) STGB(1, t + 3, 0);
        BARS; LGK0; MFMAQ(1, 0, bfr0);
        BARS;
        // ph8 (1,1)
        if (pf) STGB(1, t + 3, 1);
        BARS; MFMAQ(1, 1, bfr1);
        if (pf) { VMW10; }
        BARS;
    }

    // Epilogue: C/D layout col=lane&15, row=quad*4+reg (m89-verified).
#pragma unroll
    for (int i = 0; i < 8; i++) {
        const int row = m0 + wr * 128 + i * 16 + quad * 4;
#pragma unroll
        for (int j = 0; j < 4; j++) {
            const int col = n0 + wc * 64 + j * 16 + m16;
            if (out_mode == 3) {
                // fused QKV: block-uniform region by col>>11
                const int reg3 = col >> 11, cv = col & 2047;
                const float bb = (reg3 == 0) ? biasQ[cv]
                               : (reg3 == 1) ? bias[cv] : bias2[cv];
#pragma unroll
                for (int r = 0; r < 4; r++) {
                    const float v = acc[i][j][r] + bb;
                    if (reg3 == 2) {
                        const int bb2 = (row + r) >> 11, s = (row + r) & 2047;
                        ((ushort*)C2)[((size_t)(bb2 * HH + (cv >> 7)) * DKK + (cv & 127)) * SS + s] = f2bits(v);
                    } else {
                        ushort* dst = (ushort*)((reg3 == 0) ? CQ : C);
                        dst[(size_t)(row + r) * DD + cv] = f2bits(v);
                    }
                }
            } else if (out_mode == 4) {
                const float bb = (bias && zed == 0) ? bias[col] : 0.f;
#pragma unroll
                for (int r = 0; r < 4; r++)
                    atomicAdd((float*)C + (size_t)(row + r) * Nx + col, acc[i][j][r] + bb);
            } else {
                const float bb = bias ? bias[col] : 0.f;
#pragma unroll
                for (int r = 0; r < 4; r++) {
                    float v = acc[i][j][r] + bb;
                    const size_t idx = (size_t)(row + r) * Nx + col;
                    if (res_mode == 1)      v += ((const float*)residual)[idx];
                    else if (res_mode == 2) v += bits2f(((const ushort*)residual)[idx]);
                    if (relu) v = fmaxf(v, 0.f);
                    if (c_f32) ((float*)C)[idx] = v;
                    else       ((ushort*)C)[idx] = f2bits(v);
                }
            }
        }
    }
}

// ---------------------------------------------------------------------------
// Flash attention r8 (resubmitted unmeasured): XOR-swizzled linear LDS tiles
// + global_load_lds staging (pre-swizzled global source) + double-buffered
// K/V with counted vmcnt(8). Defer-max REVERTED (r7 regression). Q-hoist kept.
// ---------------------------------------------------------------------------
__global__ __launch_bounds__(256) void attn_kernel(const bf16t* __restrict__ q,
                                                   const bf16t* __restrict__ k,
                                                   const bf16t* __restrict__ vT,
                                                   bf16t* __restrict__ o) {
    __shared__ __align__(16) ushort KB0[64 * 128];   // 16 KiB (Q, then K even)
    __shared__ __align__(16) ushort KB1[64 * 128];   // 16 KiB (K odd)
    __shared__ __align__(16) ushort VB0[128 * 64];   // 16 KiB
    __shared__ __align__(16) ushort VB1[128 * 64];   // 16 KiB
    __shared__ __align__(16) ushort Pt[4][16 * 64];  // 8 KiB

    const int tid = threadIdx.x;
    const int wid = tid >> 6, lane = tid & 63;
    const int m16 = lane & 15, quad = lane >> 4;
    const int qt = blockIdx.x, h = blockIdx.y, b = blockIdx.z;
    const int q0 = qt * 64;
    const int sw = m16 & 7;

    const ushort* qu = (const ushort*)q;
    const ushort* ku = (const ushort*)k;
    const ushort* vu = (const ushort*)vT;
    const ushort* kbase = ku + (size_t)(b * SS) * DD + h * DKK;
    const ushort* vbase = vu + (size_t)((b * HH + h) * DKK) * SS;

    // K-shaped stage (also Q): dst[64][128], 16 instrs, wave handles 4.
    auto stageK = [&](const ushort* gb, ushort* dst) {
#pragma unroll
        for (int i = 0; i < 4; i++) {
            const int g = wid * 4 + i;
            const int row = g * 4 + (lane >> 4);
            const int sc = (lane & 15) ^ (row & 7);
            const ushort* gp = gb + (size_t)row * DD + sc * 8;
            __builtin_amdgcn_global_load_lds(
                (const __attribute__((address_space(1))) void*)gp,
                (__attribute__((address_space(3))) void*)(dst + g * 512), 16, 0, 0);
        }
    };
    // V stage: dst[128][64].
    auto stageV = [&](const ushort* gb, ushort* dst) {
#pragma unroll
        for (int i = 0; i < 4; i++) {
            const int g = wid * 4 + i;
            const int row = g * 8 + (lane >> 3);
            const int sc = (lane & 7) ^ (row & 7);
            const ushort* gp = gb + (size_t)row * SS + sc * 8;
            __builtin_amdgcn_global_load_lds(
                (const __attribute__((address_space(1))) void*)gp,
                (__attribute__((address_space(3))) void*)(dst + g * 512), 16, 0, 0);
        }
    };

    // ---- Prologue: stage Q -> KB0, hoist fragments, then K0/V0/K1/V1 ----
    stageK(qu + (size_t)(b * SS + q0) * DD + h * DKK, KB0);
    VMW0;
    BARS;
    short8 afq[4];
#pragma unroll
    for (int kk = 0; kk < 4; kk++)
        afq[kk] = *(const short8*)&KB0[(wid * 16 + m16) * 128 + (((kk * 4 + quad) ^ sw) << 3)];
    LGK0;          // reads drained before DMA overwrite of KB0
    BARS;
    stageK(kbase, KB0);
    stageV(vbase, VB0);
    stageK(kbase + (size_t)64 * DD, KB1);
    stageV(vbase + 64, VB1);
    // 16 loads in flight per wave (8 per tile)

    float m_r[4], l_r[4];
    floatx4 acc_o[8];
#pragma unroll
    for (int r = 0; r < 4; r++) { m_r[r] = -1e30f; l_r[r] = 0.f; }
#pragma unroll
    for (int t = 0; t < 8; t++) acc_o[t] = (floatx4){0.f, 0.f, 0.f, 0.f};

    const float scale = 0.08838834764831845f;   // 1/sqrt(128)
    const int nt = SS / 64;

    for (int t2 = 0; t2 < nt; t2++) {
        if (t2 + 1 < nt) { VMW8; } else { VMW0; }
        BARS;
        const ushort* Kc = (t2 & 1) ? KB1 : KB0;
        const ushort* Vc = (t2 & 1) ? VB1 : VB0;

        // QK^T: S[q=quad*4+r (+wid*16)][k=j*16+m16]
        floatx4 sacc[4];
#pragma unroll
        for (int j = 0; j < 4; j++) {
            sacc[j] = (floatx4){0.f, 0.f, 0.f, 0.f};
#pragma unroll
            for (int kk = 0; kk < 4; kk++) {
                short8 bfk = *(const short8*)&Kc[(j * 16 + m16) * 128 + (((kk * 4 + quad) ^ sw) << 3)];
                sacc[j] = __builtin_amdgcn_mfma_f32_16x16x32_bf16(afq[kk], bfk, sacc[j], 0, 0, 0);
            }
        }
        // online softmax (unconditional rescale — r5 semantics)
#pragma unroll
        for (int r = 0; r < 4; r++) {
            float s0 = sacc[0][r] * scale, s1 = sacc[1][r] * scale;
            float s2 = sacc[2][r] * scale, s3 = sacc[3][r] * scale;
            float mx = fmaxf(fmaxf(s0, s1), fmaxf(s2, s3));
#pragma unroll
            for (int off = 1; off < 16; off <<= 1) mx = fmaxf(mx, __shfl_xor(mx, off));
            const float mnew = fmaxf(m_r[r], mx);
            const float alpha = __expf(m_r[r] - mnew);
            m_r[r] = mnew;
            const float p0 = __expf(s0 - mnew), p1 = __expf(s1 - mnew);
            const float p2 = __expf(s2 - mnew), p3 = __expf(s3 - mnew);
            float rs = p0 + p1 + p2 + p3;
#pragma unroll
            for (int off = 1; off < 16; off <<= 1) rs += __shfl_xor(rs, off);
            l_r[r] = l_r[r] * alpha + rs;
#pragma unroll
            for (int t = 0; t < 8; t++) acc_o[t][r] *= alpha;
            // P write, swizzled: row rw, col c*16+m16 -> chunk (c*2+(m16>>3))^(rw&7)
            const int rw = quad * 4 + r;
            const int rb = rw * 64, rx = rw & 7, mlo = m16 & 7, mhi = m16 >> 3;
            Pt[wid][rb + (((0 + mhi) ^ rx) << 3) + mlo] = f2bits(p0);
            Pt[wid][rb + (((2 + mhi) ^ rx) << 3) + mlo] = f2bits(p1);
            Pt[wid][rb + (((4 + mhi) ^ rx) << 3) + mlo] = f2bits(p2);
            Pt[wid][rb + (((6 + mhi) ^ rx) << 3) + mlo] = f2bits(p3);
        }
        // PV: A = P[q-row=m16][k], B = V[d=t8*16+m16][k]
#pragma unroll
        for (int kk2 = 0; kk2 < 2; kk2++) {
            short8 ap = *(const short8*)&Pt[wid][m16 * 64 + (((kk2 * 4 + quad) ^ sw) << 3)];
#pragma unroll
            for (int t = 0; t < 8; t++) {
                short8 bv = *(const short8*)&Vc[(t * 16 + m16) * 64 + (((kk2 * 4 + quad) ^ sw) << 3)];
                acc_o[t] = __builtin_amdgcn_mfma_f32_16x16x32_bf16(ap, bv, acc_o[t], 0, 0, 0);
            }
        }

        LGK0;   // all waves' K/V reads drained before re-stage
        BARS;
        if (t2 + 2 < nt) {
            stageK(kbase + (size_t)((t2 + 2) * 64) * DD, (ushort*)Kc);
            stageV(vbase + (t2 + 2) * 64, (ushort*)Vc);
        }
    }

    ushort* ou = (ushort*)o;
#pragma unroll
    for (int t = 0; t < 8; t++) {
#pragma unroll
        for (int r = 0; r < 4; r++) {
            const float v = acc_o[t][r] / l_r[r];
            ou[(size_t)(b * SS + q0 + wid * 16 + quad * 4 + r) * DD + h * DKK + t * 16 + m16] = f2bits(v);
        }
    }
}

// ---------------------------------------------------------------------------
// Orchestration (unchanged from r7).
//   S0 (ws+0..16M):   n -> a (after QKV) -> n2 (after O-proj)
//   ws+16..40M:       wqkvT (24M) -> woT (8M) -> w1Th/w2Th (16M, FFN)
//   ws+40..56M:       k
//   ws+32..64M:       h (32M, FFN; wqkvT/k dead by then)
//   d_out (32M):      q (bf16, 0..16M) + vT (bf16, 16..32M) -> x1 (f32) -> out
// ---------------------------------------------------------------------------
extern "C" void kernel_launch(void* const* d_in, const int* in_sizes, int n_in,
                              void* d_out, int out_size, void* d_ws, size_t ws_size,
                              hipStream_t stream) {
    const float* x   = (const float*)d_in[0];
    // d_in[1] = mask (int32, all ones) — no-op in reference, skipped
    const float* wq = (const float*)d_in[2];  const float* bq = (const float*)d_in[3];
    const float* wk = (const float*)d_in[4];  const float* bk = (const float*)d_in[5];
    const float* wv = (const float*)d_in[6];  const float* bv = (const float*)d_in[7];
    const float* wo = (const float*)d_in[8];  const float* bo = (const float*)d_in[9];
    const float* w1 = (const float*)d_in[10]; const float* b1 = (const float*)d_in[11];
    const float* w2 = (const float*)d_in[12]; const float* b2 = (const float*)d_in[13];
    const float* g1 = (const float*)d_in[14]; const float* lb1 = (const float*)d_in[15];
    const float* g2 = (const float*)d_in[16]; const float* lb2 = (const float*)d_in[17];

    char* ws = (char*)d_ws;
    bf16t* n_buf  = (bf16t*)(ws);                      // 16 MiB
    bf16t* wqkvT  = (bf16t*)(ws + (16u << 20));        // 24 MiB
    bf16t* k_buf  = (bf16t*)(ws + (40u << 20));        // 16 MiB
    bf16t* q_buf  = (bf16t*)d_out;                     // 16 MiB (scratch)
    bf16t* vT_buf = (bf16t*)((char*)d_out + (16u << 20));  // 16 MiB (scratch)
    bf16t* a_buf  = (bf16t*)(ws);                      // after QKV (n dead)
    bf16t* woT    = (bf16t*)(ws + (16u << 20));        // after QKV (wqkvT dead)
    bf16t* n2_buf = (bf16t*)(ws);                      // after O-proj (a dead)
    bf16t* wfT    = (bf16t*)(ws + (16u << 20));        // FFN weight T (16 MiB)
    bf16t* h_buf  = (bf16t*)(ws + (32u << 20));        // 32 MiB (k dead)

    const dim3 tb(32, 8);
    const dim3 grT(DD / 32, DD / 32);            // 2048x2048 transposes
    const dim3 grO(DD / 256, MM / 256);          // (8, 16) O-proj
    const dim3 grQKV(3 * DD / 256, MM / 256);    // (24, 16) fused QKV
    const dim3 grF1(FH / 256, MM / 256);         // (16, 16) FFN1 half
    const dim3 grF2(DD / 256, MM / 256, 2);      // (8, 16, 2) FFN2 split-K

    // LN1: x(f32) -> n(bf16)
    ln_kernel<<<MM, 256, 0, stream>>>(x, g1, lb1, n_buf, 1);

    // wqkvT = [wq^T ; wk^T ; wv^T] (24 MiB), single N=6144 GEMM (384 wg)
    wtrans_kernel<<<grT, tb, 0, stream>>>(wq, wqkvT, DD, 0, 0, DD);
    wtrans_kernel<<<grT, tb, 0, stream>>>(wk, wqkvT + (size_t)DD * DD, DD, 0, 0, DD);
    wtrans_kernel<<<grT, tb, 0, stream>>>(wv, wqkvT + 2 * (size_t)DD * DD, DD, 0, 0, DD);
    gemm256<<<grQKV, 512, 0, stream>>>(n_buf, wqkvT, bk, bv, bq, nullptr, 0,
                                       k_buf, vT_buf, q_buf, 0, DD, DD, DD, DD, 0, 3);

    // woT (region free after QKV GEMM; stream-ordered)
    wtrans_kernel<<<grT, tb, 0, stream>>>(wo, woT, DD, 0, 0, DD);

    // attention -> a (S0; n dead)
    attn_kernel<<<dim3(SS / 64, HH, BB), 256, 0, stream>>>(q_buf, k_buf, vT_buf, a_buf);

    // x1 = x + a @ wo + bo -> d_out (f32; q/vT dead)
    gemm256<<<grO, 512, 0, stream>>>(a_buf, woT, bo, nullptr, nullptr, x, 1,
                                     d_out, nullptr, nullptr, 1, DD, DD, DD, DD, 0, 0);

    // LN2: x1(f32, in d_out) -> n2 (S0; a dead)
    ln_kernel<<<MM, 256, 0, stream>>>(d_out, g2, lb2, n2_buf, 1);

    // FFN in two F-halves; FFN2 split-K z=2 with f32 atomicAdd into d_out
    // (d_out already holds x1; b2 added once by z==0 blocks of half 0).
    for (int hf = 0; hf < 2; hf++) {
        const int f0 = hf * FH;
        // w1Th = w1[:, f0:f0+FH]^T (bf16 [FH][D], 16 MiB)
        wtrans_kernel<<<dim3(FH / 32, DD / 32), tb, 0, stream>>>(w1, wfT, FF, 0, f0, DD);
        // h = relu(n2 @ w1Th + b1[f0:]) (bf16 [M][FH], 32 MiB)
        gemm256<<<grF1, 512, 0, stream>>>(n2_buf, wfT, b1 + f0, nullptr, nullptr,
                                          nullptr, 0, h_buf, nullptr, nullptr,
                                          0, FH, DD, DD, DD, 1, 0);
        // w2Th = w2[f0:f0+FH, :]^T (bf16 [D][FH], 16 MiB)
        wtrans_kernel<<<dim3(DD / 32, FH / 32), tb, 0, stream>>>(w2, wfT, DD, f0, 0, FH);
        // d_out += h @ w2Th (+b2 once); split-K z=2, K=2048 each, 256 wg
        gemm256<<<grF2, 512, 0, stream>>>(h_buf, wfT, hf == 0 ? b2 : nullptr,
                                          nullptr, nullptr, nullptr, 0,
                                          d_out, nullptr, nullptr,
                                          1, DD, DD, FH, FH, 0, 4);
    }
}